// Round 13
// baseline (433.252 us; speedup 1.0000x reference)
//
#include <hip/hip_runtime.h>
#include <math.h>

// ---------------------------------------------------------------------------
// Round 13: r12 (best, 347us) + deeper latency hiding in GEMMs:
//   - non-HASA2 GEMMs: A-prefetch depth 3 (was 2)
//   - HASA2 GEMMs (h_c/h_p): A-prefetch depth 2 (was 0 -- loads were on the
//     critical path every item)
//   - grid cap 512 -> 1024 blocks (fewer serial items/wave)
// Everything else byte-identical to r12.
// ---------------------------------------------------------------------------

typedef unsigned short u16;
typedef __attribute__((ext_vector_type(8))) short s8v;   // 8 bf16 = 4 VGPR
typedef __attribute__((ext_vector_type(4))) float f4v;   // MFMA C/D frag

__device__ __forceinline__ float bf2f(u16 u) {
    unsigned x = ((unsigned)u) << 16;
    return __builtin_bit_cast(float, x);
}
__device__ __forceinline__ u16 f2bf(float f) {
    unsigned x = __builtin_bit_cast(unsigned, f);
    unsigned r = x + 0x7fffu + ((x >> 16) & 1u);
    return (u16)(r >> 16);
}
__device__ __forceinline__ unsigned pk2(float a, float b) {
    return (unsigned)f2bf(a) | ((unsigned)f2bf(b) << 16);
}
__device__ __forceinline__ void unpack8(uint4 u, float* f) {
    f[0] = bf2f((u16)(u.x & 0xffff)); f[1] = bf2f((u16)(u.x >> 16));
    f[2] = bf2f((u16)(u.y & 0xffff)); f[3] = bf2f((u16)(u.y >> 16));
    f[4] = bf2f((u16)(u.z & 0xffff)); f[5] = bf2f((u16)(u.z >> 16));
    f[6] = bf2f((u16)(u.w & 0xffff)); f[7] = bf2f((u16)(u.w >> 16));
}

// ---- small fp32 128x128 matmuls for folded weights ----
struct SmEnt { const float* A; const float* B; const float* s; };
struct SmPack { SmEnt e[4]; };

__global__ __launch_bounds__(256) void smallmm(SmPack p, float* __restrict__ out)
{
    int t = blockIdx.x * 256 + threadIdx.x;
    int m = t >> 14;
    int o = t & 16383;
    int i = o >> 7, j = o & 127;
    SmEnt en = p.e[m];
    float acc = 0.f;
#pragma unroll 4
    for (int k = 0; k < 128; ++k) acc += en.A[i * 128 + k] * en.B[k * 128 + j];
    if (en.s) acc *= *en.s;
    out[(size_t)m * 16384 + o] = acc;
}

__global__ void vecpre(
    const float* vc_bf, const float* vc_wo1, const float* vc_sp,
    const float* cv_bf, const float* cv_wo1, const float* cv_sp,
    const float* vc_bo2, const float* cv_wr,
    const float* cv_bo2, const float* out_w1, const float* out_b1,
    float* __restrict__ vout)
{
    int j = threadIdx.x;
    if (j >= 128) return;
    float a0 = 0.f, a1 = 0.f, a2 = 0.f, a3 = 0.f;
    for (int k = 0; k < 128; ++k) {
        a0 += vc_bf[k] * vc_wo1[k * 128 + j];
        a1 += cv_bf[k] * cv_wo1[k * 128 + j];
        a2 += vc_bo2[k] * cv_wr[k * 128 + j];
        a3 += cv_bo2[k] * out_w1[k * 128 + j];
    }
    vout[j] = a0 * (*vc_sp);
    vout[128 + j] = a1 * (*cv_sp);
    vout[256 + j] = a2;
    vout[384 + j] = a3 + out_b1[j];
}

// ---- weight conversion: fp32 [Ksrc][128] -> bf16 WT[col*Kdst + k], pad k ----
struct WEnt { const float* src; int Ksrc; int Kdst; };
struct WPack { WEnt e[14]; };

__global__ __launch_bounds__(256) void wconvert(WPack p, u16* __restrict__ wt)
{
    int t = blockIdx.x * 256 + threadIdx.x;
    int m = t >> 15;
    int i = t & 32767;
    WEnt en = p.e[m];
    if (i >= (en.Kdst << 7)) return;
    int k = i >> 7, col = i & 127;
    float v = (k < en.Ksrc) ? en.src[k * 128 + col] : 0.f;
    wt[(size_t)m * 32768 + (size_t)col * en.Kdst + k] = f2bf(v);
}

// ---- feature conversion (both tables): fp32 [M,F]+prenorm -> bf16 [M,96] ----
__global__ __launch_bounds__(256) void featconv2(
    const float* __restrict__ pv, const float* __restrict__ ch,
    const float* __restrict__ psh, const float* __restrict__ psc,
    const float* __restrict__ csh, const float* __restrict__ csc,
    u16* __restrict__ y, long NPr, long total, int F)
{
    for (long i = (long)blockIdx.x * 256 + threadIdx.x; i < total;
         i += (long)gridDim.x * 256) {
        int cc = (int)(i % 96);
        long r = i / 96;
        const float *x, *sh, *sc;
        long row;
        if (r < NPr) { x = pv; sh = psh; sc = psc; row = r; }
        else { x = ch; sh = csh; sc = csc; row = r - NPr; }
        float v = 0.f;
        if (cc < F) {
            v = x[row * F + cc];
            v = (v + sh[cc]) * sc[cc];
        }
        y[i] = f2bf(v);
    }
}

// ---- register-persistent-B GEMM (r8 epilogue, deeper prefetch) ----
template <int KS1, bool HASA2, bool RELU, bool GATE>
__global__ __launch_bounds__(256) void gemm_rb(
    const u16* __restrict__ A1, const u16* __restrict__ A2,
    const u16* __restrict__ WT1,     // bf16 [128][KS1*32]
    const u16* __restrict__ WT2,     // bf16 [128][128] (when HASA2)
    const float* __restrict__ bias0, // fp32 [128] or null
    const float* __restrict__ bias1, // fp32 [128] or null (gated)
    const float* __restrict__ gate,  // fp32 [M] (cnt) when GATE
    u16* __restrict__ out, int M)    // M % 16 == 0
{
    constexpr int K1 = KS1 * 32;
    constexpr int AS = KS1 + (HASA2 ? 4 : 0);
    const int lane = threadIdx.x & 63;
    const int c = lane & 15;
    const int kg = lane >> 4;
    const int wid = blockIdx.x * 4 + (threadIdx.x >> 6);
    const int ws = gridDim.x * 4;
    const int items = M >> 4;

    const u16* wbase = WT1 + (size_t)c * K1 + kg * 8;
    s8v bp[KS1][8];
#pragma unroll
    for (int ks = 0; ks < KS1; ++ks)
#pragma unroll
        for (int nt = 0; nt < 8; ++nt)
            bp[ks][nt] = *(const s8v*)(wbase + ((size_t)nt * 16) * K1 + ks * 32);

    const u16* wbase2 = HASA2 ? (WT2 + (size_t)c * 128 + kg * 8) : nullptr;

    float bc0[8], bc1[8];
#pragma unroll
    for (int nt = 0; nt < 8; ++nt) {
        bc0[nt] = bias0 ? bias0[nt * 16 + c] : 0.f;
        bc1[nt] = (GATE && bias1) ? bias1[nt * 16 + c] : 0.f;
    }

    auto lda = [&](s8v* a, int item) {
        const u16* ap = A1 + (size_t)((item << 4) + c) * K1 + kg * 8;
#pragma unroll
        for (int ks = 0; ks < KS1; ++ks) a[ks] = *(const s8v*)(ap + ks * 32);
        if (HASA2) {
            const u16* ap2 = A2 + (size_t)((item << 4) + c) * 128 + kg * 8;
#pragma unroll
            for (int ks = 0; ks < 4; ++ks) a[KS1 + ks] = *(const s8v*)(ap2 + ks * 32);
        }
    };

    // prefetch: depth 3 for !HASA2, depth 2 for HASA2
    s8v a[AS], an[AS], a2[AS];
    int item = wid;
    if (item < items) lda(a, item);
    if (item + ws < items) lda(an, item + ws);
    while (item < items) {
        const int i2 = item + 2 * ws;
        if (!HASA2 && i2 < items) lda(a2, i2);

        f4v acc[8];
#pragma unroll
        for (int nt = 0; nt < 8; ++nt) acc[nt] = (f4v){0.f, 0.f, 0.f, 0.f};
#pragma unroll
        for (int ks = 0; ks < KS1; ++ks)
#pragma unroll
            for (int nt = 0; nt < 8; ++nt)
                acc[nt] = __builtin_amdgcn_mfma_f32_16x16x32_bf16(a[ks], bp[ks][nt], acc[nt], 0, 0, 0);
        if (HASA2) {
#pragma unroll
            for (int ks = 0; ks < 4; ++ks)
#pragma unroll
                for (int nt = 0; nt < 8; ++nt) {
                    s8v b = *(const s8v*)(wbase2 + ((size_t)nt * 16) * 128 + ks * 32);
                    acc[nt] = __builtin_amdgcn_mfma_f32_16x16x32_bf16(a[KS1 + ks], b, acc[nt], 0, 0, 0);
                }
        }

        const int r0 = item << 4;
        float g4[4];
#pragma unroll
        for (int j = 0; j < 4; ++j)
            g4[j] = GATE ? (gate[r0 + kg * 4 + j] > 0.f ? 1.f : 0.f) : 0.f;
#pragma unroll
        for (int nt = 0; nt < 8; ++nt)
#pragma unroll
            for (int j = 0; j < 4; ++j) {
                float v = acc[nt][j] + bc0[nt] + g4[j] * bc1[nt];
                if (RELU) v = fmaxf(v, 0.f);
                out[(size_t)(r0 + kg * 4 + j) * 128 + nt * 16 + c] = f2bf(v);
            }

        if (!HASA2) {
#pragma unroll
            for (int ks = 0; ks < AS; ++ks) { a[ks] = an[ks]; an[ks] = a2[ks]; }
        } else {
#pragma unroll
            for (int ks = 0; ks < AS; ++ks) a[ks] = an[ks];
            if (i2 < items) lda(an, i2);
        }
        item += ws;
    }
}

// ---- multi-job GEMM (r8 epilogue, depth-3 prefetch) ----
struct GJob { const u16* A1; const u16* WT1; const float* bias0; u16* out; int M; };
struct GJobs3 { GJob j[3]; };

template <int KS1, bool RELU>
__global__ __launch_bounds__(256) void gemm_multi(GJobs3 jobs)
{
    constexpr int K1 = KS1 * 32;
    const GJob jb = jobs.j[blockIdx.y];
    const u16* __restrict__ A1 = jb.A1;
    const float* __restrict__ bias0 = jb.bias0;
    u16* __restrict__ out = jb.out;
    const int lane = threadIdx.x & 63;
    const int c = lane & 15;
    const int kg = lane >> 4;
    const int wid = blockIdx.x * 4 + (threadIdx.x >> 6);
    const int ws = gridDim.x * 4;
    const int items = jb.M >> 4;

    const u16* wbase = jb.WT1 + (size_t)c * K1 + kg * 8;
    s8v bp[KS1][8];
#pragma unroll
    for (int ks = 0; ks < KS1; ++ks)
#pragma unroll
        for (int nt = 0; nt < 8; ++nt)
            bp[ks][nt] = *(const s8v*)(wbase + ((size_t)nt * 16) * K1 + ks * 32);

    float bc0[8];
#pragma unroll
    for (int nt = 0; nt < 8; ++nt)
        bc0[nt] = bias0 ? bias0[nt * 16 + c] : 0.f;

    auto lda = [&](s8v* a, int item) {
        const u16* ap = A1 + (size_t)((item << 4) + c) * K1 + kg * 8;
#pragma unroll
        for (int ks = 0; ks < KS1; ++ks) a[ks] = *(const s8v*)(ap + ks * 32);
    };

    s8v a[KS1], an[KS1], a2[KS1], a3[KS1];
    int item = wid;
    if (item < items) lda(a, item);
    if (item + ws < items) lda(an, item + ws);
    if (item + 2 * ws < items) lda(a2, item + 2 * ws);
    while (item < items) {
        const int i3 = item + 3 * ws;
        if (i3 < items) lda(a3, i3);

        f4v acc[8];
#pragma unroll
        for (int nt = 0; nt < 8; ++nt) acc[nt] = (f4v){0.f, 0.f, 0.f, 0.f};
#pragma unroll
        for (int ks = 0; ks < KS1; ++ks)
#pragma unroll
            for (int nt = 0; nt < 8; ++nt)
                acc[nt] = __builtin_amdgcn_mfma_f32_16x16x32_bf16(a[ks], bp[ks][nt], acc[nt], 0, 0, 0);

        const int r0 = item << 4;
#pragma unroll
        for (int nt = 0; nt < 8; ++nt)
#pragma unroll
            for (int j = 0; j < 4; ++j) {
                float v = acc[nt][j] + bc0[nt];
                if (RELU) v = fmaxf(v, 0.f);
                out[(size_t)(r0 + kg * 4 + j) * 128 + nt * 16 + c] = f2bf(v);
            }

#pragma unroll
        for (int ks = 0; ks < KS1; ++ks) { a[ks] = an[ks]; an[ks] = a2[ks]; a2[ks] = a3[ks]; }
        item += ws;
    }
}

// ---- fused head: sigmoid(relu(A@W1+b1) @ w2 + b2) -> [M,2] fp32 (r8) ----
__global__ __launch_bounds__(256) void head_fused(
    const u16* __restrict__ A1, const u16* __restrict__ WT,
    const float* __restrict__ b1, const float* __restrict__ w2,
    const float* __restrict__ b2, float* __restrict__ outp, int M)
{
    constexpr int KT = 128;
    const int lane = threadIdx.x & 63;
    const int c = lane & 15;
    const int kg = lane >> 4;
    const int wid = blockIdx.x * 4 + (threadIdx.x >> 6);
    const int ws = gridDim.x * 4;
    const int items = M >> 4;

    const u16* wbase = WT + (size_t)c * KT + kg * 8;
    s8v bp[4][8];
#pragma unroll
    for (int ks = 0; ks < 4; ++ks)
#pragma unroll
        for (int nt = 0; nt < 8; ++nt)
            bp[ks][nt] = *(const s8v*)(wbase + ((size_t)nt * 16) * KT + ks * 32);

    float bc[8], w2c0[8], w2c1[8];
#pragma unroll
    for (int nt = 0; nt < 8; ++nt) {
        int col = nt * 16 + c;
        bc[nt] = b1[col];
        w2c0[nt] = w2[col * 2 + 0];
        w2c1[nt] = w2[col * 2 + 1];
    }
    const float s0 = b2[0], s1 = b2[1];

    for (int item = wid; item < items; item += ws) {
        const int r0 = item << 4;
        const u16* ap = A1 + (size_t)(r0 + c) * 128 + kg * 8;
        s8v a[4];
#pragma unroll
        for (int ks = 0; ks < 4; ++ks) a[ks] = *(const s8v*)(ap + ks * 32);

        f4v acc[8];
#pragma unroll
        for (int nt = 0; nt < 8; ++nt) acc[nt] = (f4v){0.f, 0.f, 0.f, 0.f};
#pragma unroll
        for (int ks = 0; ks < 4; ++ks)
#pragma unroll
            for (int nt = 0; nt < 8; ++nt)
                acc[nt] = __builtin_amdgcn_mfma_f32_16x16x32_bf16(a[ks], bp[ks][nt], acc[nt], 0, 0, 0);

        float pp0[4] = {0.f, 0.f, 0.f, 0.f}, pp1[4] = {0.f, 0.f, 0.f, 0.f};
#pragma unroll
        for (int nt = 0; nt < 8; ++nt)
#pragma unroll
            for (int j = 0; j < 4; ++j) {
                float v = fmaxf(acc[nt][j] + bc[nt], 0.f);
                pp0[j] += v * w2c0[nt];
                pp1[j] += v * w2c1[nt];
            }
#pragma unroll
        for (int m = 1; m < 16; m <<= 1)
#pragma unroll
            for (int j = 0; j < 4; ++j) {
                pp0[j] += __shfl_xor(pp0[j], m);
                pp1[j] += __shfl_xor(pp1[j], m);
            }
        if (c == 0) {
#pragma unroll
            for (int j = 0; j < 4; ++j) {
                int row = r0 + kg * 4 + j;
                outp[(size_t)row * 2 + 0] = 1.f / (1.f + expf(-(pp0[j] + s0)));
                outp[(size_t)row * 2 + 1] = 1.f / (1.f + expf(-(pp1[j] + s1)));
            }
        }
    }
}

// ============================ CSR counting sort ============================
__global__ __launch_bounds__(256) void binA(
    const int* __restrict__ src, const int* __restrict__ dst,
    int E, int CH, int NB, int nbk_c, int NBK,
    int* __restrict__ G, int* __restrict__ Tb)
{
    __shared__ int h[1024];
    const int blk = blockIdx.x, tid = threadIdx.x;
    for (int i = tid; i < NBK; i += 256) h[i] = 0;
    __syncthreads();
    const int e0 = blk * CH, e1 = min(E, e0 + CH);
    for (int e = e0 + tid; e < e1; e += 256) {
        atomicAdd(&h[dst[e] >> 9], 1);
        atomicAdd(&h[nbk_c + (src[e] >> 9)], 1);
    }
    __syncthreads();
    for (int b = tid; b < NBK; b += 256) {
        const int v = h[b];
        G[b * NB + blk] = v;
        if (v) atomicAdd(&Tb[b], v);
    }
}

__global__ __launch_bounds__(512) void binS(
    const int* __restrict__ Tb, int NBK, int* __restrict__ BB)
{
    __shared__ int wsum[8];
    const int tid = threadIdx.x;
    const int T = (tid < NBK) ? Tb[tid] : 0;
    const int lane = tid & 63, wv = tid >> 6;
    int incl = T;
#pragma unroll
    for (int d = 1; d < 64; d <<= 1) {
        int up = __shfl_up(incl, d);
        if (lane >= d) incl += up;
    }
    if (lane == 63) wsum[wv] = incl;
    __syncthreads();
    if (tid == 0) {
        int run = 0;
        for (int w = 0; w < 8; ++w) { int t = wsum[w]; wsum[w] = run; run += t; }
    }
    __syncthreads();
    const int base = wsum[wv] + incl - T;
    if (tid < NBK) {
        BB[tid] = base;
        if (tid == NBK - 1) BB[NBK] = base + T;
    }
}

__global__ __launch_bounds__(64) void binP(
    const int* __restrict__ G, const int* __restrict__ BB,
    int NB, int* __restrict__ PBB)
{
    const int b = blockIdx.x, l = threadIdx.x;
    const int* g = G + (size_t)b * NB;
    const int v0 = (l < NB) ? g[l] : 0;
    const int v1 = (l + 64 < NB) ? g[l + 64] : 0;
    int i0 = v0, i1 = v1;
#pragma unroll
    for (int d = 1; d < 64; d <<= 1) {
        int u0 = __shfl_up(i0, d);
        int u1 = __shfl_up(i1, d);
        if (l >= d) { i0 += u0; i1 += u1; }
    }
    const int t0 = __shfl(i0, 63);
    const int base = BB[b];
    int* p = PBB + (size_t)b * NB;
    if (l < NB) p[l] = base + i0 - v0;
    if (l + 64 < NB) p[l + 64] = base + t0 + i1 - v1;
}

__global__ __launch_bounds__(256) void binB(
    const int* __restrict__ src, const int* __restrict__ dst,
    int E, int CH, int NB, int nbk_c, int NBK,
    const int* __restrict__ PBB, unsigned* __restrict__ REC)
{
    __shared__ int fill[1024];
    const int blk = blockIdx.x, tid = threadIdx.x;
    for (int i = tid; i < NBK; i += 256) fill[i] = 0;
    __syncthreads();
    const int e0 = blk * CH, e1 = min(E, e0 + CH);
    for (int e = e0 + tid; e < e1; e += 256) {
        const int s = src[e], d = dst[e];
        const int bc = d >> 9;
        const int pc = PBB[bc * NB + blk] + atomicAdd(&fill[bc], 1);
        REC[pc] = (unsigned)s | ((unsigned)(d & 511) << 17);
        const int bp = nbk_c + (s >> 9);
        const int pp = PBB[bp * NB + blk] + atomicAdd(&fill[bp], 1);
        REC[pp] = (unsigned)d | ((unsigned)(s & 511) << 17);
    }
}

__global__ __launch_bounds__(256) void binC2(
    const unsigned* __restrict__ REC, const int* __restrict__ BB,
    int nbk_c, int NCn, int NPn,
    int* __restrict__ off_c, int* __restrict__ cnt_c,
    int* __restrict__ off_p, int* __restrict__ cnt_p, int* __restrict__ AJ)
{
    __shared__ int nh[512], lo[512], fl[512], ws2[4];
    const int b = blockIdx.x, tid = threadIdx.x;
    int Nn, node0;
    int *off_out, *cnt_out;
    if (b < nbk_c) { Nn = NCn; node0 = b << 9; off_out = off_c; cnt_out = cnt_c; }
    else { Nn = NPn; node0 = (b - nbk_c) << 9; off_out = off_p; cnt_out = cnt_p; }
    const int r0 = BB[b], r1 = BB[b + 1];
    const int kmax = min(512, Nn - node0);
    nh[tid] = 0; nh[tid + 256] = 0;
    fl[tid] = 0; fl[tid + 256] = 0;
    __syncthreads();
    for (int i = r0 + tid; i < r1; i += 256)
        atomicAdd(&nh[REC[i] >> 17], 1);
    __syncthreads();
    const int v0 = nh[2 * tid], v1 = nh[2 * tid + 1];
    const int s = v0 + v1;
    const int lane = tid & 63, wv = tid >> 6;
    int incl = s;
#pragma unroll
    for (int d = 1; d < 64; d <<= 1) {
        int up = __shfl_up(incl, d);
        if (lane >= d) incl += up;
    }
    if (lane == 63) ws2[wv] = incl;
    __syncthreads();
    if (tid == 0) {
        int run = 0;
        for (int w = 0; w < 4; ++w) { int t = ws2[w]; ws2[w] = run; run += t; }
    }
    __syncthreads();
    const int base = ws2[wv] + incl - s;
    lo[2 * tid] = base;
    lo[2 * tid + 1] = base + v0;
    __syncthreads();
    for (int k = tid; k < kmax; k += 256) {
        off_out[node0 + k] = r0 + lo[k];
        cnt_out[node0 + k] = nh[k];
    }
    for (int i = r0 + tid; i < r1; i += 256) {
        const unsigned rec = REC[i];
        const int k = rec >> 17;
        const int pos = r0 + lo[k] + atomicAdd(&fl[k], 1);
        AJ[pos] = (int)(rec & 0x1FFFFu);
    }
}

// ---- gather: Sdiv[n] = mean_e relu((RW[n]+LW[adj])*sf) ----
__global__ __launch_bounds__(256) void node_gather2(
    const int* __restrict__ off, const int* __restrict__ cnt,
    const int* __restrict__ adj,
    const u16* __restrict__ RW, const u16* __restrict__ LW,
    u16* __restrict__ Sdiv, float* __restrict__ cntf,
    const float* __restrict__ sf_p, int N)
{
    int t = blockIdx.x * 256 + threadIdx.x;
    int n = t >> 5;
    if (n >= N) return;
    int l32 = t & 31;
    int c = l32 & 15;
    int half = l32 >> 4;
    const float sf = *sf_p;
    const int start = off[n], len = cnt[n];

    float rw[8];
    unpack8(*(const uint4*)(RW + (size_t)n * 128 + c * 8), rw);
    float acc[8] = {0.f, 0.f, 0.f, 0.f, 0.f, 0.f, 0.f, 0.f};

    for (int i = half; i < len; i += 2) {
        int l = adj[start + i];
        float lw[8];
        unpack8(*(const uint4*)(LW + (size_t)l * 128 + c * 8), lw);
#pragma unroll
        for (int j = 0; j < 8; ++j)
            acc[j] += fmaxf((rw[j] + lw[j]) * sf, 0.f);
    }
#pragma unroll
    for (int j = 0; j < 8; ++j) acc[j] += __shfl_xor(acc[j], 16);

    if (half == 0) {
        float inv = 1.f / fmaxf((float)len, 1.f);
        uint4 o;
        o.x = pk2(acc[0] * inv, acc[1] * inv);
        o.y = pk2(acc[2] * inv, acc[3] * inv);
        o.z = pk2(acc[4] * inv, acc[5] * inv);
        o.w = pk2(acc[6] * inv, acc[7] * inv);
        *(uint4*)(Sdiv + (size_t)n * 128 + c * 8) = o;
        if (l32 == 0) cntf[n] = (float)len;
    }
}

extern "C" void kernel_launch(void* const* d_in, const int* in_sizes, int n_in,
                              void* d_out, int out_size, void* d_ws, size_t ws_size,
                              hipStream_t stream)
{
    const float* pivot = (const float*)d_in[0];
    const float* child = (const float*)d_in[1];
    const int* edges = (const int*)d_in[2];
    const int F = in_sizes[3];           // 69
    const int NP = in_sizes[0] / F;
    const int NC = in_sizes[1] / F;
    const int E = in_sizes[2] / 2;
    const int* src = edges;
    const int* dst = edges + E;

    const float *pe_shift = (const float*)d_in[3], *pe_scale = (const float*)d_in[4],
                *pe_w1 = (const float*)d_in[5], *pe_b1 = (const float*)d_in[6],
                *pe_w2 = (const float*)d_in[7], *pe_b2 = (const float*)d_in[8];
    const float *ce_shift = (const float*)d_in[9], *ce_scale = (const float*)d_in[10],
                *ce_w1 = (const float*)d_in[11], *ce_b1 = (const float*)d_in[12],
                *ce_w2 = (const float*)d_in[13], *ce_b2 = (const float*)d_in[14];
    const float *vc_wl = (const float*)d_in[15], *vc_bl = (const float*)d_in[16],
                *vc_wr = (const float*)d_in[17], *vc_sf = (const float*)d_in[18],
                *vc_wf = (const float*)d_in[19], *vc_bf = (const float*)d_in[20],
                *vc_sp = (const float*)d_in[21], *vc_wo1 = (const float*)d_in[22],
                *vc_bo1 = (const float*)d_in[23], *vc_wo2 = (const float*)d_in[24],
                *vc_bo2 = (const float*)d_in[25];
    const float *cv_wl = (const float*)d_in[26], *cv_bl = (const float*)d_in[27],
                *cv_wr = (const float*)d_in[28], *cv_sf = (const float*)d_in[29],
                *cv_wf = (const float*)d_in[30], *cv_bf = (const float*)d_in[31],
                *cv_sp = (const float*)d_in[32], *cv_wo1 = (const float*)d_in[33],
                *cv_bo1 = (const float*)d_in[34], *cv_wo2 = (const float*)d_in[35],
                *cv_bo2 = (const float*)d_in[36];
    const float *out_w1 = (const float*)d_in[37], *out_b1 = (const float*)d_in[38],
                *out_w2 = (const float*)d_in[39], *out_b2 = (const float*)d_in[40];

    // ---- workspace carve (256B aligned) ----
    char* base = (char*)d_ws;
    size_t off = 0;
    auto carve = [&](size_t bytes) {
        void* p = base + off;
        off += (bytes + 255) & ~(size_t)255;
        return p;
    };
    float* Wsc = (float*)carve((size_t)4 * 16384 * 4);
    float* Vsc = (float*)carve((size_t)4 * 128 * 4);
    u16* WT = (u16*)carve((size_t)14 * 32768 * 2);
    u16* FPC = (u16*)carve((size_t)(NP + NC) * 96 * 2);
    u16* FP = FPC;
    u16* FC = FPC + (size_t)NP * 96;
    u16* B0 = (u16*)carve((size_t)NP * 128 * 2);   // pv0
    u16* B1 = (u16*)carve((size_t)NC * 128 * 2);
    u16* B2 = (u16*)carve((size_t)NC * 128 * 2);   // ch0
    u16* B3 = (u16*)carve((size_t)NC * 128 * 2);   // LW_v -> LW_c
    u16* B4 = (u16*)carve((size_t)NC * 128 * 2);   // Sdiv
    u16* B5 = (u16*)carve((size_t)NC * 128 * 2);   // embed temp / h_c
    u16* B6 = (u16*)carve((size_t)NP * 128 * 2);   // RW_p
    const int NMAX = (NC > NP) ? NC : NP;
    float* cntf = (float*)carve((size_t)NMAX * 4);

    const int NB = 120;
    const int CH = (E + NB - 1) / NB;
    const int nbk_c = (NC + 511) >> 9;
    const int nbk_p = (NP + 511) >> 9;
    const int NBK = nbk_c + nbk_p;
    int* cnt_c = (int*)carve((size_t)NC * 4);
    int* cnt_p = (int*)carve((size_t)NP * 4);
    int* off_c = (int*)carve((size_t)NC * 4);
    int* off_p = (int*)carve((size_t)NP * 4);
    int* G = (int*)carve((size_t)NBK * NB * 4);
    int* PBB = (int*)carve((size_t)NBK * NB * 4);
    int* BB = (int*)carve((size_t)(NBK + 1) * 4);
    int* Tb = (int*)carve((size_t)NBK * 4);
    unsigned* REC = (unsigned*)carve((size_t)2 * E * 4);
    int* AJ = (int*)carve((size_t)2 * E * 4);

    // ---- folded weight precompute (fp32) ----
    SmPack sp;
    sp.e[0] = {vc_wf, vc_wo1, vc_sp};
    sp.e[1] = {cv_wf, cv_wo1, cv_sp};
    sp.e[2] = {vc_wo2, cv_wr, nullptr};
    sp.e[3] = {cv_wo2, out_w1, nullptr};
    hipLaunchKernelGGL(smallmm, dim3(256), dim3(256), 0, stream, sp, Wsc);
    hipLaunchKernelGGL(vecpre, dim3(1), dim3(128), 0, stream,
                       vc_bf, vc_wo1, vc_sp, cv_bf, cv_wo1, cv_sp,
                       vc_bo2, cv_wr, cv_bo2, out_w1, out_b1, Vsc);
    const float* cvec_vc = Vsc;
    const float* cvec_cv = Vsc + 128;
    const float* cx = Vsc + 256;
    const float* bh = Vsc + 384;

    // ---- weight conversion ----
    WPack wp;
    auto setw = [&](int i, const float* s, int ks, int kd) {
        wp.e[i].src = s; wp.e[i].Ksrc = ks; wp.e[i].Kdst = kd;
    };
    setw(0, pe_w1, F, 96);            setw(1, pe_w2, 128, 128);
    setw(2, ce_w1, F, 96);            setw(3, ce_w2, 128, 128);
    setw(4, vc_wl, 128, 128);         setw(5, vc_wr, 128, 128);
    setw(6, Wsc + 0 * 16384, 128, 128);
    setw(7, vc_wo1 + 128 * 128, 128, 128);
    setw(8, Wsc + 2 * 16384, 128, 128);
    setw(9, cv_wl, 128, 128);         setw(10, cv_wr, 128, 128);
    setw(11, Wsc + 1 * 16384, 128, 128);
    setw(12, cv_wo1 + 128 * 128, 128, 128);
    setw(13, Wsc + 3 * 16384, 128, 128);
    hipLaunchKernelGGL(wconvert, dim3(14 * 128), dim3(256), 0, stream, wp, WT);
    auto wt = [&](int i) { return WT + (size_t)i * 32768; };

    // ---- feature conversion (both tables, one dispatch) ----
    hipLaunchKernelGGL(featconv2, dim3(2048), dim3(256), 0, stream,
                       pivot, child, pe_shift, pe_scale, ce_shift, ce_scale,
                       FPC, (long)NP, (long)(NP + NC) * 96, F);

    // ---- CSR via counting sort ----
    hipMemsetAsync(Tb, 0, (size_t)NBK * 4, stream);
    hipLaunchKernelGGL(binA, dim3(NB), dim3(256), 0, stream,
                       src, dst, E, CH, NB, nbk_c, NBK, G, Tb);
    hipLaunchKernelGGL(binS, dim3(1), dim3(512), 0, stream, Tb, NBK, BB);
    hipLaunchKernelGGL(binP, dim3(NBK), dim3(64), 0, stream, G, BB, NB, PBB);
    hipLaunchKernelGGL(binB, dim3(NB), dim3(256), 0, stream,
                       src, dst, E, CH, NB, nbk_c, NBK, PBB, REC);
    hipLaunchKernelGGL(binC2, dim3(NBK), dim3(256), 0, stream,
                       REC, BB, nbk_c, NC, NP, off_c, cnt_c, off_p, cnt_p, AJ);

    // ---- GEMM pipeline ----
    const dim3 blk(256);
    auto grd = [](int M) {
        int items = M >> 4;
        int b = (items + 3) / 4;
        return dim3((unsigned)(b < 1024 ? b : 1024));
    };

    // embeddings layer 1 (batched): FP->B1 (NP), FC->B5 (NC)
    {
        GJobs3 j;
        j.j[0] = {FP, wt(0), pe_b1, B1, NP};
        j.j[1] = {FC, wt(2), ce_b1, B5, NC};
        j.j[2] = j.j[0];
        dim3 g = grd(NC); g.y = 2;
        hipLaunchKernelGGL(HIP_KERNEL_NAME(gemm_multi<3, true>), g, blk, 0, stream, j);
    }
    // embeddings layer 2 (batched): B1->B0 (pv0), B5->B2 (ch0)
    {
        GJobs3 j;
        j.j[0] = {B1, wt(1), pe_b2, B0, NP};
        j.j[1] = {B5, wt(3), ce_b2, B2, NC};
        j.j[2] = j.j[0];
        dim3 g = grd(NC); g.y = 2;
        hipLaunchKernelGGL(HIP_KERNEL_NAME(gemm_multi<4, true>), g, blk, 0, stream, j);
    }
    // RW_c / LW_v / RW_p (batched)
    {
        GJobs3 j;
        j.j[0] = {B2, wt(4), vc_bl, B1, NC};    // RW_c = ch0@wl+bl
        j.j[1] = {B0, wt(5), nullptr, B3, NP};  // LW_v = pv0@wr
        j.j[2] = {B0, wt(9), cv_bl, B6, NP};    // RW_p = pv0@cv_wl+bl
        dim3 g = grd(NC); g.y = 3;
        hipLaunchKernelGGL(HIP_KERNEL_NAME(gemm_multi<4, false>), g, blk, 0, stream, j);
    }

    // conv v->c
    hipLaunchKernelGGL(node_gather2, dim3(((size_t)NC * 32 + 255) / 256), blk, 0,
                       stream, off_c, cnt_c, AJ, B1, B3, B4, cntf, vc_sf, NC);
    gemm_rb<4, true, true, true><<<grd(NC), blk, 0, stream>>>(
        B4, B2, wt(6), wt(7), vc_bo1, cvec_vc, cntf, B5, NC);            // h_c
    gemm_rb<4, false, false, false><<<grd(NC), blk, 0, stream>>>(
        B5, nullptr, wt(8), nullptr, cx, nullptr, nullptr, B3, NC);      // LW_c

    // conv c->v
    hipLaunchKernelGGL(node_gather2, dim3(((size_t)NP * 32 + 255) / 256), blk, 0,
                       stream, off_p, cnt_p, AJ, B6, B3, B4, cntf, cv_sf, NP);
    gemm_rb<4, true, true, true><<<grd(NP), blk, 0, stream>>>(
        B4, B0, wt(11), wt(12), cv_bo1, cvec_cv, cntf, B1, NP);          // h_p

    // head on h_p with folded W1'=Wh, b1'=bh
    hipLaunchKernelGGL(head_fused, grd(NP), blk, 0, stream,
                       B1, wt(13), bh, out_w2, out_b2, (float*)d_out, NP);
}

// Round 14
// 336.209 us; speedup vs baseline: 1.2886x; 1.2886x over previous
//
#include <hip/hip_runtime.h>
#include <math.h>

// ---------------------------------------------------------------------------
// Round 14: r12 exact (best, 347us; r13's deeper-prefetch/1024-grid reverted)
// + ONE change: gemm_multi epilogue stores via wave-private LDS bounce ->
// 4 coalesced 1KB dwordx4 stores per item (was 32 scattered 2B stores),
// attacking vmem store-issue/vmcnt pressure.
// ---------------------------------------------------------------------------

typedef unsigned short u16;
typedef __attribute__((ext_vector_type(8))) short s8v;   // 8 bf16 = 4 VGPR
typedef __attribute__((ext_vector_type(4))) float f4v;   // MFMA C/D frag

__device__ __forceinline__ float bf2f(u16 u) {
    unsigned x = ((unsigned)u) << 16;
    return __builtin_bit_cast(float, x);
}
__device__ __forceinline__ u16 f2bf(float f) {
    unsigned x = __builtin_bit_cast(unsigned, f);
    unsigned r = x + 0x7fffu + ((x >> 16) & 1u);
    return (u16)(r >> 16);
}
__device__ __forceinline__ unsigned pk2(float a, float b) {
    return (unsigned)f2bf(a) | ((unsigned)f2bf(b) << 16);
}
__device__ __forceinline__ void unpack8(uint4 u, float* f) {
    f[0] = bf2f((u16)(u.x & 0xffff)); f[1] = bf2f((u16)(u.x >> 16));
    f[2] = bf2f((u16)(u.y & 0xffff)); f[3] = bf2f((u16)(u.y >> 16));
    f[4] = bf2f((u16)(u.z & 0xffff)); f[5] = bf2f((u16)(u.z >> 16));
    f[6] = bf2f((u16)(u.w & 0xffff)); f[7] = bf2f((u16)(u.w >> 16));
}

// ---- small fp32 128x128 matmuls for folded weights ----
struct SmEnt { const float* A; const float* B; const float* s; };
struct SmPack { SmEnt e[4]; };

__global__ __launch_bounds__(256) void smallmm(SmPack p, float* __restrict__ out)
{
    int t = blockIdx.x * 256 + threadIdx.x;
    int m = t >> 14;
    int o = t & 16383;
    int i = o >> 7, j = o & 127;
    SmEnt en = p.e[m];
    float acc = 0.f;
#pragma unroll 4
    for (int k = 0; k < 128; ++k) acc += en.A[i * 128 + k] * en.B[k * 128 + j];
    if (en.s) acc *= *en.s;
    out[(size_t)m * 16384 + o] = acc;
}

__global__ void vecpre(
    const float* vc_bf, const float* vc_wo1, const float* vc_sp,
    const float* cv_bf, const float* cv_wo1, const float* cv_sp,
    const float* vc_bo2, const float* cv_wr,
    const float* cv_bo2, const float* out_w1, const float* out_b1,
    float* __restrict__ vout)
{
    int j = threadIdx.x;
    if (j >= 128) return;
    float a0 = 0.f, a1 = 0.f, a2 = 0.f, a3 = 0.f;
    for (int k = 0; k < 128; ++k) {
        a0 += vc_bf[k] * vc_wo1[k * 128 + j];
        a1 += cv_bf[k] * cv_wo1[k * 128 + j];
        a2 += vc_bo2[k] * cv_wr[k * 128 + j];
        a3 += cv_bo2[k] * out_w1[k * 128 + j];
    }
    vout[j] = a0 * (*vc_sp);
    vout[128 + j] = a1 * (*cv_sp);
    vout[256 + j] = a2;
    vout[384 + j] = a3 + out_b1[j];
}

// ---- weight conversion: fp32 [Ksrc][128] -> bf16 WT[col*Kdst + k], pad k ----
struct WEnt { const float* src; int Ksrc; int Kdst; };
struct WPack { WEnt e[14]; };

__global__ __launch_bounds__(256) void wconvert(WPack p, u16* __restrict__ wt)
{
    int t = blockIdx.x * 256 + threadIdx.x;
    int m = t >> 15;
    int i = t & 32767;
    WEnt en = p.e[m];
    if (i >= (en.Kdst << 7)) return;
    int k = i >> 7, col = i & 127;
    float v = (k < en.Ksrc) ? en.src[k * 128 + col] : 0.f;
    wt[(size_t)m * 32768 + (size_t)col * en.Kdst + k] = f2bf(v);
}

// ---- feature conversion (both tables): fp32 [M,F]+prenorm -> bf16 [M,96] ----
__global__ __launch_bounds__(256) void featconv2(
    const float* __restrict__ pv, const float* __restrict__ ch,
    const float* __restrict__ psh, const float* __restrict__ psc,
    const float* __restrict__ csh, const float* __restrict__ csc,
    u16* __restrict__ y, long NPr, long total, int F)
{
    for (long i = (long)blockIdx.x * 256 + threadIdx.x; i < total;
         i += (long)gridDim.x * 256) {
        int cc = (int)(i % 96);
        long r = i / 96;
        const float *x, *sh, *sc;
        long row;
        if (r < NPr) { x = pv; sh = psh; sc = psc; row = r; }
        else { x = ch; sh = csh; sc = csc; row = r - NPr; }
        float v = 0.f;
        if (cc < F) {
            v = x[row * F + cc];
            v = (v + sh[cc]) * sc[cc];
        }
        y[i] = f2bf(v);
    }
}

// ---- register-persistent-B GEMM (r12 exact) ----
template <int KS1, bool HASA2, bool RELU, bool GATE>
__global__ __launch_bounds__(256) void gemm_rb(
    const u16* __restrict__ A1, const u16* __restrict__ A2,
    const u16* __restrict__ WT1,     // bf16 [128][KS1*32]
    const u16* __restrict__ WT2,     // bf16 [128][128] (when HASA2)
    const float* __restrict__ bias0, // fp32 [128] or null
    const float* __restrict__ bias1, // fp32 [128] or null (gated)
    const float* __restrict__ gate,  // fp32 [M] (cnt) when GATE
    u16* __restrict__ out, int M)    // M % 16 == 0
{
    constexpr int K1 = KS1 * 32;
    constexpr bool PF = !HASA2;
    constexpr int AS = KS1 + (HASA2 ? 4 : 0);
    const int lane = threadIdx.x & 63;
    const int c = lane & 15;
    const int kg = lane >> 4;
    const int wid = blockIdx.x * 4 + (threadIdx.x >> 6);
    const int ws = gridDim.x * 4;
    const int items = M >> 4;

    const u16* wbase = WT1 + (size_t)c * K1 + kg * 8;
    s8v bp[KS1][8];
#pragma unroll
    for (int ks = 0; ks < KS1; ++ks)
#pragma unroll
        for (int nt = 0; nt < 8; ++nt)
            bp[ks][nt] = *(const s8v*)(wbase + ((size_t)nt * 16) * K1 + ks * 32);

    const u16* wbase2 = HASA2 ? (WT2 + (size_t)c * 128 + kg * 8) : nullptr;

    float bc0[8], bc1[8];
#pragma unroll
    for (int nt = 0; nt < 8; ++nt) {
        bc0[nt] = bias0 ? bias0[nt * 16 + c] : 0.f;
        bc1[nt] = (GATE && bias1) ? bias1[nt * 16 + c] : 0.f;
    }

    auto lda = [&](s8v* a, int item) {
        const u16* ap = A1 + (size_t)((item << 4) + c) * K1 + kg * 8;
#pragma unroll
        for (int ks = 0; ks < KS1; ++ks) a[ks] = *(const s8v*)(ap + ks * 32);
        if (HASA2) {
            const u16* ap2 = A2 + (size_t)((item << 4) + c) * 128 + kg * 8;
#pragma unroll
            for (int ks = 0; ks < 4; ++ks) a[KS1 + ks] = *(const s8v*)(ap2 + ks * 32);
        }
    };

    s8v a[AS], an[AS], a2[AS];
    int item = wid;
    if (item < items) lda(a, item);
    if (PF && item + ws < items) lda(an, item + ws);
    while (item < items) {
        const int i2 = item + 2 * ws;
        if (PF && i2 < items) lda(a2, i2);

        f4v acc[8];
#pragma unroll
        for (int nt = 0; nt < 8; ++nt) acc[nt] = (f4v){0.f, 0.f, 0.f, 0.f};
#pragma unroll
        for (int ks = 0; ks < KS1; ++ks)
#pragma unroll
            for (int nt = 0; nt < 8; ++nt)
                acc[nt] = __builtin_amdgcn_mfma_f32_16x16x32_bf16(a[ks], bp[ks][nt], acc[nt], 0, 0, 0);
        if (HASA2) {
#pragma unroll
            for (int ks = 0; ks < 4; ++ks)
#pragma unroll
                for (int nt = 0; nt < 8; ++nt) {
                    s8v b = *(const s8v*)(wbase2 + ((size_t)nt * 16) * 128 + ks * 32);
                    acc[nt] = __builtin_amdgcn_mfma_f32_16x16x32_bf16(a[KS1 + ks], b, acc[nt], 0, 0, 0);
                }
        }

        const int r0 = item << 4;
        float g4[4];
#pragma unroll
        for (int j = 0; j < 4; ++j)
            g4[j] = GATE ? (gate[r0 + kg * 4 + j] > 0.f ? 1.f : 0.f) : 0.f;
#pragma unroll
        for (int nt = 0; nt < 8; ++nt)
#pragma unroll
            for (int j = 0; j < 4; ++j) {
                float v = acc[nt][j] + bc0[nt] + g4[j] * bc1[nt];
                if (RELU) v = fmaxf(v, 0.f);
                out[(size_t)(r0 + kg * 4 + j) * 128 + nt * 16 + c] = f2bf(v);
            }

        if (PF) {
#pragma unroll
            for (int ks = 0; ks < AS; ++ks) { a[ks] = an[ks]; an[ks] = a2[ks]; }
        } else if (item + ws < items) {
            lda(a, item + ws);
        }
        item += ws;
    }
}

// ---- multi-job GEMM: r12 + LDS-bounce coalesced store epilogue ----
struct GJob { const u16* A1; const u16* WT1; const float* bias0; u16* out; int M; };
struct GJobs3 { GJob j[3]; };

template <int KS1, bool RELU>
__global__ __launch_bounds__(256) void gemm_multi(GJobs3 jobs)
{
    constexpr int K1 = KS1 * 32;
    __shared__ u16 tile[4][16 * 136];
    const GJob jb = jobs.j[blockIdx.y];
    const u16* __restrict__ A1 = jb.A1;
    const float* __restrict__ bias0 = jb.bias0;
    u16* __restrict__ out = jb.out;
    const int lane = threadIdx.x & 63;
    const int c = lane & 15;
    const int kg = lane >> 4;
    const int wv = threadIdx.x >> 6;
    const int wid = blockIdx.x * 4 + wv;
    const int ws = gridDim.x * 4;
    const int items = jb.M >> 4;
    u16* tl = tile[wv];

    const u16* wbase = jb.WT1 + (size_t)c * K1 + kg * 8;
    s8v bp[KS1][8];
#pragma unroll
    for (int ks = 0; ks < KS1; ++ks)
#pragma unroll
        for (int nt = 0; nt < 8; ++nt)
            bp[ks][nt] = *(const s8v*)(wbase + ((size_t)nt * 16) * K1 + ks * 32);

    float bc0[8];
#pragma unroll
    for (int nt = 0; nt < 8; ++nt)
        bc0[nt] = bias0 ? bias0[nt * 16 + c] : 0.f;

    auto lda = [&](s8v* a, int item) {
        const u16* ap = A1 + (size_t)((item << 4) + c) * K1 + kg * 8;
#pragma unroll
        for (int ks = 0; ks < KS1; ++ks) a[ks] = *(const s8v*)(ap + ks * 32);
    };

    s8v a[KS1], an[KS1], a2[KS1];
    int item = wid;
    if (item < items) lda(a, item);
    if (item + ws < items) lda(an, item + ws);
    while (item < items) {
        const int i2 = item + 2 * ws;
        if (i2 < items) lda(a2, i2);

        f4v acc[8];
#pragma unroll
        for (int nt = 0; nt < 8; ++nt) acc[nt] = (f4v){0.f, 0.f, 0.f, 0.f};
#pragma unroll
        for (int ks = 0; ks < KS1; ++ks)
#pragma unroll
            for (int nt = 0; nt < 8; ++nt)
                acc[nt] = __builtin_amdgcn_mfma_f32_16x16x32_bf16(a[ks], bp[ks][nt], acc[nt], 0, 0, 0);

        const int r0 = item << 4;
        // stage fragments to wave-private LDS tile (no barrier needed)
#pragma unroll
        for (int nt = 0; nt < 8; ++nt)
#pragma unroll
            for (int j = 0; j < 4; ++j) {
                float v = acc[nt][j] + bc0[nt];
                if (RELU) v = fmaxf(v, 0.f);
                tl[(kg * 4 + j) * 136 + nt * 16 + c] = f2bf(v);
            }
        // 4 coalesced 1KB stores: f = k*512 + lane*8 walks the 16x128 tile
#pragma unroll
        for (int k = 0; k < 4; ++k) {
            const int f = k * 512 + lane * 8;
            const int row = f >> 7, col = f & 127;
            uint4 v = *(const uint4*)&tl[row * 136 + col];
            *(uint4*)&out[(size_t)r0 * 128 + f] = v;
        }

#pragma unroll
        for (int ks = 0; ks < KS1; ++ks) { a[ks] = an[ks]; an[ks] = a2[ks]; }
        item += ws;
    }
}

// ---- fused head: sigmoid(relu(A@W1+b1) @ w2 + b2) -> [M,2] fp32 (r8) ----
__global__ __launch_bounds__(256) void head_fused(
    const u16* __restrict__ A1, const u16* __restrict__ WT,
    const float* __restrict__ b1, const float* __restrict__ w2,
    const float* __restrict__ b2, float* __restrict__ outp, int M)
{
    constexpr int KT = 128;
    const int lane = threadIdx.x & 63;
    const int c = lane & 15;
    const int kg = lane >> 4;
    const int wid = blockIdx.x * 4 + (threadIdx.x >> 6);
    const int ws = gridDim.x * 4;
    const int items = M >> 4;

    const u16* wbase = WT + (size_t)c * KT + kg * 8;
    s8v bp[4][8];
#pragma unroll
    for (int ks = 0; ks < 4; ++ks)
#pragma unroll
        for (int nt = 0; nt < 8; ++nt)
            bp[ks][nt] = *(const s8v*)(wbase + ((size_t)nt * 16) * KT + ks * 32);

    float bc[8], w2c0[8], w2c1[8];
#pragma unroll
    for (int nt = 0; nt < 8; ++nt) {
        int col = nt * 16 + c;
        bc[nt] = b1[col];
        w2c0[nt] = w2[col * 2 + 0];
        w2c1[nt] = w2[col * 2 + 1];
    }
    const float s0 = b2[0], s1 = b2[1];

    for (int item = wid; item < items; item += ws) {
        const int r0 = item << 4;
        const u16* ap = A1 + (size_t)(r0 + c) * 128 + kg * 8;
        s8v a[4];
#pragma unroll
        for (int ks = 0; ks < 4; ++ks) a[ks] = *(const s8v*)(ap + ks * 32);

        f4v acc[8];
#pragma unroll
        for (int nt = 0; nt < 8; ++nt) acc[nt] = (f4v){0.f, 0.f, 0.f, 0.f};
#pragma unroll
        for (int ks = 0; ks < 4; ++ks)
#pragma unroll
            for (int nt = 0; nt < 8; ++nt)
                acc[nt] = __builtin_amdgcn_mfma_f32_16x16x32_bf16(a[ks], bp[ks][nt], acc[nt], 0, 0, 0);

        float pp0[4] = {0.f, 0.f, 0.f, 0.f}, pp1[4] = {0.f, 0.f, 0.f, 0.f};
#pragma unroll
        for (int nt = 0; nt < 8; ++nt)
#pragma unroll
            for (int j = 0; j < 4; ++j) {
                float v = fmaxf(acc[nt][j] + bc[nt], 0.f);
                pp0[j] += v * w2c0[nt];
                pp1[j] += v * w2c1[nt];
            }
#pragma unroll
        for (int m = 1; m < 16; m <<= 1)
#pragma unroll
            for (int j = 0; j < 4; ++j) {
                pp0[j] += __shfl_xor(pp0[j], m);
                pp1[j] += __shfl_xor(pp1[j], m);
            }
        if (c == 0) {
#pragma unroll
            for (int j = 0; j < 4; ++j) {
                int row = r0 + kg * 4 + j;
                outp[(size_t)row * 2 + 0] = 1.f / (1.f + expf(-(pp0[j] + s0)));
                outp[(size_t)row * 2 + 1] = 1.f / (1.f + expf(-(pp1[j] + s1)));
            }
        }
    }
}

// ============================ CSR counting sort ============================
__global__ __launch_bounds__(256) void binA(
    const int* __restrict__ src, const int* __restrict__ dst,
    int E, int CH, int NB, int nbk_c, int NBK,
    int* __restrict__ G, int* __restrict__ Tb)
{
    __shared__ int h[1024];
    const int blk = blockIdx.x, tid = threadIdx.x;
    for (int i = tid; i < NBK; i += 256) h[i] = 0;
    __syncthreads();
    const int e0 = blk * CH, e1 = min(E, e0 + CH);
    for (int e = e0 + tid; e < e1; e += 256) {
        atomicAdd(&h[dst[e] >> 9], 1);
        atomicAdd(&h[nbk_c + (src[e] >> 9)], 1);
    }
    __syncthreads();
    for (int b = tid; b < NBK; b += 256) {
        const int v = h[b];
        G[b * NB + blk] = v;
        if (v) atomicAdd(&Tb[b], v);
    }
}

__global__ __launch_bounds__(512) void binS(
    const int* __restrict__ Tb, int NBK, int* __restrict__ BB)
{
    __shared__ int wsum[8];
    const int tid = threadIdx.x;
    const int T = (tid < NBK) ? Tb[tid] : 0;
    const int lane = tid & 63, wv = tid >> 6;
    int incl = T;
#pragma unroll
    for (int d = 1; d < 64; d <<= 1) {
        int up = __shfl_up(incl, d);
        if (lane >= d) incl += up;
    }
    if (lane == 63) wsum[wv] = incl;
    __syncthreads();
    if (tid == 0) {
        int run = 0;
        for (int w = 0; w < 8; ++w) { int t = wsum[w]; wsum[w] = run; run += t; }
    }
    __syncthreads();
    const int base = wsum[wv] + incl - T;
    if (tid < NBK) {
        BB[tid] = base;
        if (tid == NBK - 1) BB[NBK] = base + T;
    }
}

__global__ __launch_bounds__(64) void binP(
    const int* __restrict__ G, const int* __restrict__ BB,
    int NB, int* __restrict__ PBB)
{
    const int b = blockIdx.x, l = threadIdx.x;
    const int* g = G + (size_t)b * NB;
    const int v0 = (l < NB) ? g[l] : 0;
    const int v1 = (l + 64 < NB) ? g[l + 64] : 0;
    int i0 = v0, i1 = v1;
#pragma unroll
    for (int d = 1; d < 64; d <<= 1) {
        int u0 = __shfl_up(i0, d);
        int u1 = __shfl_up(i1, d);
        if (l >= d) { i0 += u0; i1 += u1; }
    }
    const int t0 = __shfl(i0, 63);
    const int base = BB[b];
    int* p = PBB + (size_t)b * NB;
    if (l < NB) p[l] = base + i0 - v0;
    if (l + 64 < NB) p[l + 64] = base + t0 + i1 - v1;
}

__global__ __launch_bounds__(256) void binB(
    const int* __restrict__ src, const int* __restrict__ dst,
    int E, int CH, int NB, int nbk_c, int NBK,
    const int* __restrict__ PBB, unsigned* __restrict__ REC)
{
    __shared__ int fill[1024];
    const int blk = blockIdx.x, tid = threadIdx.x;
    for (int i = tid; i < NBK; i += 256) fill[i] = 0;
    __syncthreads();
    const int e0 = blk * CH, e1 = min(E, e0 + CH);
    for (int e = e0 + tid; e < e1; e += 256) {
        const int s = src[e], d = dst[e];
        const int bc = d >> 9;
        const int pc = PBB[bc * NB + blk] + atomicAdd(&fill[bc], 1);
        REC[pc] = (unsigned)s | ((unsigned)(d & 511) << 17);
        const int bp = nbk_c + (s >> 9);
        const int pp = PBB[bp * NB + blk] + atomicAdd(&fill[bp], 1);
        REC[pp] = (unsigned)d | ((unsigned)(s & 511) << 17);
    }
}

__global__ __launch_bounds__(256) void binC2(
    const unsigned* __restrict__ REC, const int* __restrict__ BB,
    int nbk_c, int NCn, int NPn,
    int* __restrict__ off_c, int* __restrict__ cnt_c,
    int* __restrict__ off_p, int* __restrict__ cnt_p, int* __restrict__ AJ)
{
    __shared__ int nh[512], lo[512], fl[512], ws2[4];
    const int b = blockIdx.x, tid = threadIdx.x;
    int Nn, node0;
    int *off_out, *cnt_out;
    if (b < nbk_c) { Nn = NCn; node0 = b << 9; off_out = off_c; cnt_out = cnt_c; }
    else { Nn = NPn; node0 = (b - nbk_c) << 9; off_out = off_p; cnt_out = cnt_p; }
    const int r0 = BB[b], r1 = BB[b + 1];
    const int kmax = min(512, Nn - node0);
    nh[tid] = 0; nh[tid + 256] = 0;
    fl[tid] = 0; fl[tid + 256] = 0;
    __syncthreads();
    for (int i = r0 + tid; i < r1; i += 256)
        atomicAdd(&nh[REC[i] >> 17], 1);
    __syncthreads();
    const int v0 = nh[2 * tid], v1 = nh[2 * tid + 1];
    const int s = v0 + v1;
    const int lane = tid & 63, wv = tid >> 6;
    int incl = s;
#pragma unroll
    for (int d = 1; d < 64; d <<= 1) {
        int up = __shfl_up(incl, d);
        if (lane >= d) incl += up;
    }
    if (lane == 63) ws2[wv] = incl;
    __syncthreads();
    if (tid == 0) {
        int run = 0;
        for (int w = 0; w < 4; ++w) { int t = ws2[w]; ws2[w] = run; run += t; }
    }
    __syncthreads();
    const int base = ws2[wv] + incl - s;
    lo[2 * tid] = base;
    lo[2 * tid + 1] = base + v0;
    __syncthreads();
    for (int k = tid; k < kmax; k += 256) {
        off_out[node0 + k] = r0 + lo[k];
        cnt_out[node0 + k] = nh[k];
    }
    for (int i = r0 + tid; i < r1; i += 256) {
        const unsigned rec = REC[i];
        const int k = rec >> 17;
        const int pos = r0 + lo[k] + atomicAdd(&fl[k], 1);
        AJ[pos] = (int)(rec & 0x1FFFFu);
    }
}

// ---- gather: Sdiv[n] = mean_e relu((RW[n]+LW[adj])*sf) ----
__global__ __launch_bounds__(256) void node_gather2(
    const int* __restrict__ off, const int* __restrict__ cnt,
    const int* __restrict__ adj,
    const u16* __restrict__ RW, const u16* __restrict__ LW,
    u16* __restrict__ Sdiv, float* __restrict__ cntf,
    const float* __restrict__ sf_p, int N)
{
    int t = blockIdx.x * 256 + threadIdx.x;
    int n = t >> 5;
    if (n >= N) return;
    int l32 = t & 31;
    int c = l32 & 15;
    int half = l32 >> 4;
    const float sf = *sf_p;
    const int start = off[n], len = cnt[n];

    float rw[8];
    unpack8(*(const uint4*)(RW + (size_t)n * 128 + c * 8), rw);
    float acc[8] = {0.f, 0.f, 0.f, 0.f, 0.f, 0.f, 0.f, 0.f};

    for (int i = half; i < len; i += 2) {
        int l = adj[start + i];
        float lw[8];
        unpack8(*(const uint4*)(LW + (size_t)l * 128 + c * 8), lw);
#pragma unroll
        for (int j = 0; j < 8; ++j)
            acc[j] += fmaxf((rw[j] + lw[j]) * sf, 0.f);
    }
#pragma unroll
    for (int j = 0; j < 8; ++j) acc[j] += __shfl_xor(acc[j], 16);

    if (half == 0) {
        float inv = 1.f / fmaxf((float)len, 1.f);
        uint4 o;
        o.x = pk2(acc[0] * inv, acc[1] * inv);
        o.y = pk2(acc[2] * inv, acc[3] * inv);
        o.z = pk2(acc[4] * inv, acc[5] * inv);
        o.w = pk2(acc[6] * inv, acc[7] * inv);
        *(uint4*)(Sdiv + (size_t)n * 128 + c * 8) = o;
        if (l32 == 0) cntf[n] = (float)len;
    }
}

extern "C" void kernel_launch(void* const* d_in, const int* in_sizes, int n_in,
                              void* d_out, int out_size, void* d_ws, size_t ws_size,
                              hipStream_t stream)
{
    const float* pivot = (const float*)d_in[0];
    const float* child = (const float*)d_in[1];
    const int* edges = (const int*)d_in[2];
    const int F = in_sizes[3];           // 69
    const int NP = in_sizes[0] / F;
    const int NC = in_sizes[1] / F;
    const int E = in_sizes[2] / 2;
    const int* src = edges;
    const int* dst = edges + E;

    const float *pe_shift = (const float*)d_in[3], *pe_scale = (const float*)d_in[4],
                *pe_w1 = (const float*)d_in[5], *pe_b1 = (const float*)d_in[6],
                *pe_w2 = (const float*)d_in[7], *pe_b2 = (const float*)d_in[8];
    const float *ce_shift = (const float*)d_in[9], *ce_scale = (const float*)d_in[10],
                *ce_w1 = (const float*)d_in[11], *ce_b1 = (const float*)d_in[12],
                *ce_w2 = (const float*)d_in[13], *ce_b2 = (const float*)d_in[14];
    const float *vc_wl = (const float*)d_in[15], *vc_bl = (const float*)d_in[16],
                *vc_wr = (const float*)d_in[17], *vc_sf = (const float*)d_in[18],
                *vc_wf = (const float*)d_in[19], *vc_bf = (const float*)d_in[20],
                *vc_sp = (const float*)d_in[21], *vc_wo1 = (const float*)d_in[22],
                *vc_bo1 = (const float*)d_in[23], *vc_wo2 = (const float*)d_in[24],
                *vc_bo2 = (const float*)d_in[25];
    const float *cv_wl = (const float*)d_in[26], *cv_bl = (const float*)d_in[27],
                *cv_wr = (const float*)d_in[28], *cv_sf = (const float*)d_in[29],
                *cv_wf = (const float*)d_in[30], *cv_bf = (const float*)d_in[31],
                *cv_sp = (const float*)d_in[32], *cv_wo1 = (const float*)d_in[33],
                *cv_bo1 = (const float*)d_in[34], *cv_wo2 = (const float*)d_in[35],
                *cv_bo2 = (const float*)d_in[36];
    const float *out_w1 = (const float*)d_in[37], *out_b1 = (const float*)d_in[38],
                *out_w2 = (const float*)d_in[39], *out_b2 = (const float*)d_in[40];

    // ---- workspace carve (256B aligned) ----
    char* base = (char*)d_ws;
    size_t off = 0;
    auto carve = [&](size_t bytes) {
        void* p = base + off;
        off += (bytes + 255) & ~(size_t)255;
        return p;
    };
    float* Wsc = (float*)carve((size_t)4 * 16384 * 4);
    float* Vsc = (float*)carve((size_t)4 * 128 * 4);
    u16* WT = (u16*)carve((size_t)14 * 32768 * 2);
    u16* FPC = (u16*)carve((size_t)(NP + NC) * 96 * 2);
    u16* FP = FPC;
    u16* FC = FPC + (size_t)NP * 96;
    u16* B0 = (u16*)carve((size_t)NP * 128 * 2);   // pv0
    u16* B1 = (u16*)carve((size_t)NC * 128 * 2);
    u16* B2 = (u16*)carve((size_t)NC * 128 * 2);   // ch0
    u16* B3 = (u16*)carve((size_t)NC * 128 * 2);   // LW_v -> LW_c
    u16* B4 = (u16*)carve((size_t)NC * 128 * 2);   // Sdiv
    u16* B5 = (u16*)carve((size_t)NC * 128 * 2);   // embed temp / h_c
    u16* B6 = (u16*)carve((size_t)NP * 128 * 2);   // RW_p
    const int NMAX = (NC > NP) ? NC : NP;
    float* cntf = (float*)carve((size_t)NMAX * 4);

    const int NB = 120;
    const int CH = (E + NB - 1) / NB;
    const int nbk_c = (NC + 511) >> 9;
    const int nbk_p = (NP + 511) >> 9;
    const int NBK = nbk_c + nbk_p;
    int* cnt_c = (int*)carve((size_t)NC * 4);
    int* cnt_p = (int*)carve((size_t)NP * 4);
    int* off_c = (int*)carve((size_t)NC * 4);
    int* off_p = (int*)carve((size_t)NP * 4);
    int* G = (int*)carve((size_t)NBK * NB * 4);
    int* PBB = (int*)carve((size_t)NBK * NB * 4);
    int* BB = (int*)carve((size_t)(NBK + 1) * 4);
    int* Tb = (int*)carve((size_t)NBK * 4);
    unsigned* REC = (unsigned*)carve((size_t)2 * E * 4);
    int* AJ = (int*)carve((size_t)2 * E * 4);

    // ---- folded weight precompute (fp32) ----
    SmPack sp;
    sp.e[0] = {vc_wf, vc_wo1, vc_sp};
    sp.e[1] = {cv_wf, cv_wo1, cv_sp};
    sp.e[2] = {vc_wo2, cv_wr, nullptr};
    sp.e[3] = {cv_wo2, out_w1, nullptr};
    hipLaunchKernelGGL(smallmm, dim3(256), dim3(256), 0, stream, sp, Wsc);
    hipLaunchKernelGGL(vecpre, dim3(1), dim3(128), 0, stream,
                       vc_bf, vc_wo1, vc_sp, cv_bf, cv_wo1, cv_sp,
                       vc_bo2, cv_wr, cv_bo2, out_w1, out_b1, Vsc);
    const float* cvec_vc = Vsc;
    const float* cvec_cv = Vsc + 128;
    const float* cx = Vsc + 256;
    const float* bh = Vsc + 384;

    // ---- weight conversion ----
    WPack wp;
    auto setw = [&](int i, const float* s, int ks, int kd) {
        wp.e[i].src = s; wp.e[i].Ksrc = ks; wp.e[i].Kdst = kd;
    };
    setw(0, pe_w1, F, 96);            setw(1, pe_w2, 128, 128);
    setw(2, ce_w1, F, 96);            setw(3, ce_w2, 128, 128);
    setw(4, vc_wl, 128, 128);         setw(5, vc_wr, 128, 128);
    setw(6, Wsc + 0 * 16384, 128, 128);
    setw(7, vc_wo1 + 128 * 128, 128, 128);
    setw(8, Wsc + 2 * 16384, 128, 128);
    setw(9, cv_wl, 128, 128);         setw(10, cv_wr, 128, 128);
    setw(11, Wsc + 1 * 16384, 128, 128);
    setw(12, cv_wo1 + 128 * 128, 128, 128);
    setw(13, Wsc + 3 * 16384, 128, 128);
    hipLaunchKernelGGL(wconvert, dim3(14 * 128), dim3(256), 0, stream, wp, WT);
    auto wt = [&](int i) { return WT + (size_t)i * 32768; };

    // ---- feature conversion (both tables, one dispatch) ----
    hipLaunchKernelGGL(featconv2, dim3(2048), dim3(256), 0, stream,
                       pivot, child, pe_shift, pe_scale, ce_shift, ce_scale,
                       FPC, (long)NP, (long)(NP + NC) * 96, F);

    // ---- CSR via counting sort ----
    hipMemsetAsync(Tb, 0, (size_t)NBK * 4, stream);
    hipLaunchKernelGGL(binA, dim3(NB), dim3(256), 0, stream,
                       src, dst, E, CH, NB, nbk_c, NBK, G, Tb);
    hipLaunchKernelGGL(binS, dim3(1), dim3(512), 0, stream, Tb, NBK, BB);
    hipLaunchKernelGGL(binP, dim3(NBK), dim3(64), 0, stream, G, BB, NB, PBB);
    hipLaunchKernelGGL(binB, dim3(NB), dim3(256), 0, stream,
                       src, dst, E, CH, NB, nbk_c, NBK, PBB, REC);
    hipLaunchKernelGGL(binC2, dim3(NBK), dim3(256), 0, stream,
                       REC, BB, nbk_c, NC, NP, off_c, cnt_c, off_p, cnt_p, AJ);

    // ---- GEMM pipeline ----
    const dim3 blk(256);
    auto grd = [](int M) {
        int items = M >> 4;
        int b = (items + 3) / 4;
        return dim3((unsigned)(b < 512 ? b : 512));
    };

    // embeddings layer 1 (batched): FP->B1 (NP), FC->B5 (NC)
    {
        GJobs3 j;
        j.j[0] = {FP, wt(0), pe_b1, B1, NP};
        j.j[1] = {FC, wt(2), ce_b1, B5, NC};
        j.j[2] = j.j[0];
        dim3 g = grd(NC); g.y = 2;
        hipLaunchKernelGGL(HIP_KERNEL_NAME(gemm_multi<3, true>), g, blk, 0, stream, j);
    }
    // embeddings layer 2 (batched): B1->B0 (pv0), B5->B2 (ch0)
    {
        GJobs3 j;
        j.j[0] = {B1, wt(1), pe_b2, B0, NP};
        j.j[1] = {B5, wt(3), ce_b2, B2, NC};
        j.j[2] = j.j[0];
        dim3 g = grd(NC); g.y = 2;
        hipLaunchKernelGGL(HIP_KERNEL_NAME(gemm_multi<4, true>), g, blk, 0, stream, j);
    }
    // RW_c / LW_v / RW_p (batched)
    {
        GJobs3 j;
        j.j[0] = {B2, wt(4), vc_bl, B1, NC};    // RW_c = ch0@wl+bl
        j.j[1] = {B0, wt(5), nullptr, B3, NP};  // LW_v = pv0@wr
        j.j[2] = {B0, wt(9), cv_bl, B6, NP};    // RW_p = pv0@cv_wl+bl
        dim3 g = grd(NC); g.y = 3;
        hipLaunchKernelGGL(HIP_KERNEL_NAME(gemm_multi<4, false>), g, blk, 0, stream, j);
    }

    // conv v->c
    hipLaunchKernelGGL(node_gather2, dim3(((size_t)NC * 32 + 255) / 256), blk, 0,
                       stream, off_c, cnt_c, AJ, B1, B3, B4, cntf, vc_sf, NC);
    gemm_rb<4, true, true, true><<<grd(NC), blk, 0, stream>>>(
        B4, B2, wt(6), wt(7), vc_bo1, cvec_vc, cntf, B5, NC);            // h_c
    gemm_rb<4, false, false, false><<<grd(NC), blk, 0, stream>>>(
        B5, nullptr, wt(8), nullptr, cx, nullptr, nullptr, B3, NC);      // LW_c

    // conv c->v
    hipLaunchKernelGGL(node_gather2, dim3(((size_t)NP * 32 + 255) / 256), blk, 0,
                       stream, off_p, cnt_p, AJ, B6, B3, B4, cntf, cv_sf, NP);
    gemm_rb<4, true, true, true><<<grd(NP), blk, 0, stream>>>(
        B4, B0, wt(11), wt(12), cv_bo1, cvec_cv, cntf, B1, NP);          // h_p

    // head on h_p with folded W1'=Wh, b1'=bh
    hipLaunchKernelGGL(head_fused, grd(NP), blk, 0, stream,
                       B1, wt(13), bh, out_w2, out_b2, (float*)d_out, NP);
}

// Round 15
// 330.235 us; speedup vs baseline: 1.3119x; 1.0181x over previous
//
#include <hip/hip_runtime.h>
#include <math.h>

// ---------------------------------------------------------------------------
// Round 15: r14 (best, 336us) + division-free coalesced featconv3.
//   r14's featconv2 spent 36% VALU on 64-bit i%96, i/96 per element.
//   featconv3: 8 rows x 32 lanes per block; lane l -> cols {l, l+32, l+64};
//   pure shift/mask indexing, coalesced fp32 reads + u16 writes.
// Everything else byte-identical to r14.
// ---------------------------------------------------------------------------

typedef unsigned short u16;
typedef __attribute__((ext_vector_type(8))) short s8v;   // 8 bf16 = 4 VGPR
typedef __attribute__((ext_vector_type(4))) float f4v;   // MFMA C/D frag

__device__ __forceinline__ float bf2f(u16 u) {
    unsigned x = ((unsigned)u) << 16;
    return __builtin_bit_cast(float, x);
}
__device__ __forceinline__ u16 f2bf(float f) {
    unsigned x = __builtin_bit_cast(unsigned, f);
    unsigned r = x + 0x7fffu + ((x >> 16) & 1u);
    return (u16)(r >> 16);
}
__device__ __forceinline__ unsigned pk2(float a, float b) {
    return (unsigned)f2bf(a) | ((unsigned)f2bf(b) << 16);
}
__device__ __forceinline__ void unpack8(uint4 u, float* f) {
    f[0] = bf2f((u16)(u.x & 0xffff)); f[1] = bf2f((u16)(u.x >> 16));
    f[2] = bf2f((u16)(u.y & 0xffff)); f[3] = bf2f((u16)(u.y >> 16));
    f[4] = bf2f((u16)(u.z & 0xffff)); f[5] = bf2f((u16)(u.z >> 16));
    f[6] = bf2f((u16)(u.w & 0xffff)); f[7] = bf2f((u16)(u.w >> 16));
}

// ---- small fp32 128x128 matmuls for folded weights ----
struct SmEnt { const float* A; const float* B; const float* s; };
struct SmPack { SmEnt e[4]; };

__global__ __launch_bounds__(256) void smallmm(SmPack p, float* __restrict__ out)
{
    int t = blockIdx.x * 256 + threadIdx.x;
    int m = t >> 14;
    int o = t & 16383;
    int i = o >> 7, j = o & 127;
    SmEnt en = p.e[m];
    float acc = 0.f;
#pragma unroll 4
    for (int k = 0; k < 128; ++k) acc += en.A[i * 128 + k] * en.B[k * 128 + j];
    if (en.s) acc *= *en.s;
    out[(size_t)m * 16384 + o] = acc;
}

__global__ void vecpre(
    const float* vc_bf, const float* vc_wo1, const float* vc_sp,
    const float* cv_bf, const float* cv_wo1, const float* cv_sp,
    const float* vc_bo2, const float* cv_wr,
    const float* cv_bo2, const float* out_w1, const float* out_b1,
    float* __restrict__ vout)
{
    int j = threadIdx.x;
    if (j >= 128) return;
    float a0 = 0.f, a1 = 0.f, a2 = 0.f, a3 = 0.f;
    for (int k = 0; k < 128; ++k) {
        a0 += vc_bf[k] * vc_wo1[k * 128 + j];
        a1 += cv_bf[k] * cv_wo1[k * 128 + j];
        a2 += vc_bo2[k] * cv_wr[k * 128 + j];
        a3 += cv_bo2[k] * out_w1[k * 128 + j];
    }
    vout[j] = a0 * (*vc_sp);
    vout[128 + j] = a1 * (*cv_sp);
    vout[256 + j] = a2;
    vout[384 + j] = a3 + out_b1[j];
}

// ---- weight conversion: fp32 [Ksrc][128] -> bf16 WT[col*Kdst + k], pad k ----
struct WEnt { const float* src; int Ksrc; int Kdst; };
struct WPack { WEnt e[14]; };

__global__ __launch_bounds__(256) void wconvert(WPack p, u16* __restrict__ wt)
{
    int t = blockIdx.x * 256 + threadIdx.x;
    int m = t >> 15;
    int i = t & 32767;
    WEnt en = p.e[m];
    if (i >= (en.Kdst << 7)) return;
    int k = i >> 7, col = i & 127;
    float v = (k < en.Ksrc) ? en.src[k * 128 + col] : 0.f;
    wt[(size_t)m * 32768 + (size_t)col * en.Kdst + k] = f2bf(v);
}

// ---- feature conversion: division-free, coalesced ----
// 8 rows x 32 lanes per block; lane l handles cols {l, l+32, l+64}.
__global__ __launch_bounds__(256) void featconv3(
    const float* __restrict__ pv, const float* __restrict__ ch,
    const float* __restrict__ psh, const float* __restrict__ psc,
    const float* __restrict__ csh, const float* __restrict__ csc,
    u16* __restrict__ y, int NPr, int NTOT, int F)
{
    const int l = threadIdx.x & 31;
    const int rl = threadIdx.x >> 5;
    for (int row = blockIdx.x * 8 + rl; row < NTOT; row += gridDim.x * 8) {
        const float *x, *sh, *sc;
        int r;
        if (row < NPr) { x = pv; sh = psh; sc = psc; r = row; }
        else { x = ch; sh = csh; sc = csc; r = row - NPr; }
        const float* xr = x + (size_t)r * F;
        u16* yr = y + (size_t)row * 96;
#pragma unroll
        for (int k = 0; k < 3; ++k) {
            const int cc = l + k * 32;
            float v = 0.f;
            if (cc < F) v = (xr[cc] + sh[cc]) * sc[cc];
            yr[cc] = f2bf(v);
        }
    }
}

// ---- register-persistent-B GEMM (r12 exact) ----
template <int KS1, bool HASA2, bool RELU, bool GATE>
__global__ __launch_bounds__(256) void gemm_rb(
    const u16* __restrict__ A1, const u16* __restrict__ A2,
    const u16* __restrict__ WT1,     // bf16 [128][KS1*32]
    const u16* __restrict__ WT2,     // bf16 [128][128] (when HASA2)
    const float* __restrict__ bias0, // fp32 [128] or null
    const float* __restrict__ bias1, // fp32 [128] or null (gated)
    const float* __restrict__ gate,  // fp32 [M] (cnt) when GATE
    u16* __restrict__ out, int M)    // M % 16 == 0
{
    constexpr int K1 = KS1 * 32;
    constexpr bool PF = !HASA2;
    constexpr int AS = KS1 + (HASA2 ? 4 : 0);
    const int lane = threadIdx.x & 63;
    const int c = lane & 15;
    const int kg = lane >> 4;
    const int wid = blockIdx.x * 4 + (threadIdx.x >> 6);
    const int ws = gridDim.x * 4;
    const int items = M >> 4;

    const u16* wbase = WT1 + (size_t)c * K1 + kg * 8;
    s8v bp[KS1][8];
#pragma unroll
    for (int ks = 0; ks < KS1; ++ks)
#pragma unroll
        for (int nt = 0; nt < 8; ++nt)
            bp[ks][nt] = *(const s8v*)(wbase + ((size_t)nt * 16) * K1 + ks * 32);

    const u16* wbase2 = HASA2 ? (WT2 + (size_t)c * 128 + kg * 8) : nullptr;

    float bc0[8], bc1[8];
#pragma unroll
    for (int nt = 0; nt < 8; ++nt) {
        bc0[nt] = bias0 ? bias0[nt * 16 + c] : 0.f;
        bc1[nt] = (GATE && bias1) ? bias1[nt * 16 + c] : 0.f;
    }

    auto lda = [&](s8v* a, int item) {
        const u16* ap = A1 + (size_t)((item << 4) + c) * K1 + kg * 8;
#pragma unroll
        for (int ks = 0; ks < KS1; ++ks) a[ks] = *(const s8v*)(ap + ks * 32);
        if (HASA2) {
            const u16* ap2 = A2 + (size_t)((item << 4) + c) * 128 + kg * 8;
#pragma unroll
            for (int ks = 0; ks < 4; ++ks) a[KS1 + ks] = *(const s8v*)(ap2 + ks * 32);
        }
    };

    s8v a[AS], an[AS], a2[AS];
    int item = wid;
    if (item < items) lda(a, item);
    if (PF && item + ws < items) lda(an, item + ws);
    while (item < items) {
        const int i2 = item + 2 * ws;
        if (PF && i2 < items) lda(a2, i2);

        f4v acc[8];
#pragma unroll
        for (int nt = 0; nt < 8; ++nt) acc[nt] = (f4v){0.f, 0.f, 0.f, 0.f};
#pragma unroll
        for (int ks = 0; ks < KS1; ++ks)
#pragma unroll
            for (int nt = 0; nt < 8; ++nt)
                acc[nt] = __builtin_amdgcn_mfma_f32_16x16x32_bf16(a[ks], bp[ks][nt], acc[nt], 0, 0, 0);
        if (HASA2) {
#pragma unroll
            for (int ks = 0; ks < 4; ++ks)
#pragma unroll
                for (int nt = 0; nt < 8; ++nt) {
                    s8v b = *(const s8v*)(wbase2 + ((size_t)nt * 16) * 128 + ks * 32);
                    acc[nt] = __builtin_amdgcn_mfma_f32_16x16x32_bf16(a[KS1 + ks], b, acc[nt], 0, 0, 0);
                }
        }

        const int r0 = item << 4;
        float g4[4];
#pragma unroll
        for (int j = 0; j < 4; ++j)
            g4[j] = GATE ? (gate[r0 + kg * 4 + j] > 0.f ? 1.f : 0.f) : 0.f;
#pragma unroll
        for (int nt = 0; nt < 8; ++nt)
#pragma unroll
            for (int j = 0; j < 4; ++j) {
                float v = acc[nt][j] + bc0[nt] + g4[j] * bc1[nt];
                if (RELU) v = fmaxf(v, 0.f);
                out[(size_t)(r0 + kg * 4 + j) * 128 + nt * 16 + c] = f2bf(v);
            }

        if (PF) {
#pragma unroll
            for (int ks = 0; ks < AS; ++ks) { a[ks] = an[ks]; an[ks] = a2[ks]; }
        } else if (item + ws < items) {
            lda(a, item + ws);
        }
        item += ws;
    }
}

// ---- multi-job GEMM: r14 (LDS-bounce coalesced store epilogue) ----
struct GJob { const u16* A1; const u16* WT1; const float* bias0; u16* out; int M; };
struct GJobs3 { GJob j[3]; };

template <int KS1, bool RELU>
__global__ __launch_bounds__(256) void gemm_multi(GJobs3 jobs)
{
    constexpr int K1 = KS1 * 32;
    __shared__ u16 tile[4][16 * 136];
    const GJob jb = jobs.j[blockIdx.y];
    const u16* __restrict__ A1 = jb.A1;
    const float* __restrict__ bias0 = jb.bias0;
    u16* __restrict__ out = jb.out;
    const int lane = threadIdx.x & 63;
    const int c = lane & 15;
    const int kg = lane >> 4;
    const int wv = threadIdx.x >> 6;
    const int wid = blockIdx.x * 4 + wv;
    const int ws = gridDim.x * 4;
    const int items = jb.M >> 4;
    u16* tl = tile[wv];

    const u16* wbase = jb.WT1 + (size_t)c * K1 + kg * 8;
    s8v bp[KS1][8];
#pragma unroll
    for (int ks = 0; ks < KS1; ++ks)
#pragma unroll
        for (int nt = 0; nt < 8; ++nt)
            bp[ks][nt] = *(const s8v*)(wbase + ((size_t)nt * 16) * K1 + ks * 32);

    float bc0[8];
#pragma unroll
    for (int nt = 0; nt < 8; ++nt)
        bc0[nt] = bias0 ? bias0[nt * 16 + c] : 0.f;

    auto lda = [&](s8v* a, int item) {
        const u16* ap = A1 + (size_t)((item << 4) + c) * K1 + kg * 8;
#pragma unroll
        for (int ks = 0; ks < KS1; ++ks) a[ks] = *(const s8v*)(ap + ks * 32);
    };

    s8v a[KS1], an[KS1], a2[KS1];
    int item = wid;
    if (item < items) lda(a, item);
    if (item + ws < items) lda(an, item + ws);
    while (item < items) {
        const int i2 = item + 2 * ws;
        if (i2 < items) lda(a2, i2);

        f4v acc[8];
#pragma unroll
        for (int nt = 0; nt < 8; ++nt) acc[nt] = (f4v){0.f, 0.f, 0.f, 0.f};
#pragma unroll
        for (int ks = 0; ks < KS1; ++ks)
#pragma unroll
            for (int nt = 0; nt < 8; ++nt)
                acc[nt] = __builtin_amdgcn_mfma_f32_16x16x32_bf16(a[ks], bp[ks][nt], acc[nt], 0, 0, 0);

        const int r0 = item << 4;
#pragma unroll
        for (int nt = 0; nt < 8; ++nt)
#pragma unroll
            for (int j = 0; j < 4; ++j) {
                float v = acc[nt][j] + bc0[nt];
                if (RELU) v = fmaxf(v, 0.f);
                tl[(kg * 4 + j) * 136 + nt * 16 + c] = f2bf(v);
            }
#pragma unroll
        for (int k = 0; k < 4; ++k) {
            const int f = k * 512 + lane * 8;
            const int row = f >> 7, col = f & 127;
            uint4 v = *(const uint4*)&tl[row * 136 + col];
            *(uint4*)&out[(size_t)r0 * 128 + f] = v;
        }

#pragma unroll
        for (int ks = 0; ks < KS1; ++ks) { a[ks] = an[ks]; an[ks] = a2[ks]; }
        item += ws;
    }
}

// ---- fused head: sigmoid(relu(A@W1+b1) @ w2 + b2) -> [M,2] fp32 (r8) ----
__global__ __launch_bounds__(256) void head_fused(
    const u16* __restrict__ A1, const u16* __restrict__ WT,
    const float* __restrict__ b1, const float* __restrict__ w2,
    const float* __restrict__ b2, float* __restrict__ outp, int M)
{
    constexpr int KT = 128;
    const int lane = threadIdx.x & 63;
    const int c = lane & 15;
    const int kg = lane >> 4;
    const int wid = blockIdx.x * 4 + (threadIdx.x >> 6);
    const int ws = gridDim.x * 4;
    const int items = M >> 4;

    const u16* wbase = WT + (size_t)c * KT + kg * 8;
    s8v bp[4][8];
#pragma unroll
    for (int ks = 0; ks < 4; ++ks)
#pragma unroll
        for (int nt = 0; nt < 8; ++nt)
            bp[ks][nt] = *(const s8v*)(wbase + ((size_t)nt * 16) * KT + ks * 32);

    float bc[8], w2c0[8], w2c1[8];
#pragma unroll
    for (int nt = 0; nt < 8; ++nt) {
        int col = nt * 16 + c;
        bc[nt] = b1[col];
        w2c0[nt] = w2[col * 2 + 0];
        w2c1[nt] = w2[col * 2 + 1];
    }
    const float s0 = b2[0], s1 = b2[1];

    for (int item = wid; item < items; item += ws) {
        const int r0 = item << 4;
        const u16* ap = A1 + (size_t)(r0 + c) * 128 + kg * 8;
        s8v a[4];
#pragma unroll
        for (int ks = 0; ks < 4; ++ks) a[ks] = *(const s8v*)(ap + ks * 32);

        f4v acc[8];
#pragma unroll
        for (int nt = 0; nt < 8; ++nt) acc[nt] = (f4v){0.f, 0.f, 0.f, 0.f};
#pragma unroll
        for (int ks = 0; ks < 4; ++ks)
#pragma unroll
            for (int nt = 0; nt < 8; ++nt)
                acc[nt] = __builtin_amdgcn_mfma_f32_16x16x32_bf16(a[ks], bp[ks][nt], acc[nt], 0, 0, 0);

        float pp0[4] = {0.f, 0.f, 0.f, 0.f}, pp1[4] = {0.f, 0.f, 0.f, 0.f};
#pragma unroll
        for (int nt = 0; nt < 8; ++nt)
#pragma unroll
            for (int j = 0; j < 4; ++j) {
                float v = fmaxf(acc[nt][j] + bc[nt], 0.f);
                pp0[j] += v * w2c0[nt];
                pp1[j] += v * w2c1[nt];
            }
#pragma unroll
        for (int m = 1; m < 16; m <<= 1)
#pragma unroll
            for (int j = 0; j < 4; ++j) {
                pp0[j] += __shfl_xor(pp0[j], m);
                pp1[j] += __shfl_xor(pp1[j], m);
            }
        if (c == 0) {
#pragma unroll
            for (int j = 0; j < 4; ++j) {
                int row = r0 + kg * 4 + j;
                outp[(size_t)row * 2 + 0] = 1.f / (1.f + expf(-(pp0[j] + s0)));
                outp[(size_t)row * 2 + 1] = 1.f / (1.f + expf(-(pp1[j] + s1)));
            }
        }
    }
}

// ============================ CSR counting sort ============================
__global__ __launch_bounds__(256) void binA(
    const int* __restrict__ src, const int* __restrict__ dst,
    int E, int CH, int NB, int nbk_c, int NBK,
    int* __restrict__ G, int* __restrict__ Tb)
{
    __shared__ int h[1024];
    const int blk = blockIdx.x, tid = threadIdx.x;
    for (int i = tid; i < NBK; i += 256) h[i] = 0;
    __syncthreads();
    const int e0 = blk * CH, e1 = min(E, e0 + CH);
    for (int e = e0 + tid; e < e1; e += 256) {
        atomicAdd(&h[dst[e] >> 9], 1);
        atomicAdd(&h[nbk_c + (src[e] >> 9)], 1);
    }
    __syncthreads();
    for (int b = tid; b < NBK; b += 256) {
        const int v = h[b];
        G[b * NB + blk] = v;
        if (v) atomicAdd(&Tb[b], v);
    }
}

__global__ __launch_bounds__(512) void binS(
    const int* __restrict__ Tb, int NBK, int* __restrict__ BB)
{
    __shared__ int wsum[8];
    const int tid = threadIdx.x;
    const int T = (tid < NBK) ? Tb[tid] : 0;
    const int lane = tid & 63, wv = tid >> 6;
    int incl = T;
#pragma unroll
    for (int d = 1; d < 64; d <<= 1) {
        int up = __shfl_up(incl, d);
        if (lane >= d) incl += up;
    }
    if (lane == 63) wsum[wv] = incl;
    __syncthreads();
    if (tid == 0) {
        int run = 0;
        for (int w = 0; w < 8; ++w) { int t = wsum[w]; wsum[w] = run; run += t; }
    }
    __syncthreads();
    const int base = wsum[wv] + incl - T;
    if (tid < NBK) {
        BB[tid] = base;
        if (tid == NBK - 1) BB[NBK] = base + T;
    }
}

__global__ __launch_bounds__(64) void binP(
    const int* __restrict__ G, const int* __restrict__ BB,
    int NB, int* __restrict__ PBB)
{
    const int b = blockIdx.x, l = threadIdx.x;
    const int* g = G + (size_t)b * NB;
    const int v0 = (l < NB) ? g[l] : 0;
    const int v1 = (l + 64 < NB) ? g[l + 64] : 0;
    int i0 = v0, i1 = v1;
#pragma unroll
    for (int d = 1; d < 64; d <<= 1) {
        int u0 = __shfl_up(i0, d);
        int u1 = __shfl_up(i1, d);
        if (l >= d) { i0 += u0; i1 += u1; }
    }
    const int t0 = __shfl(i0, 63);
    const int base = BB[b];
    int* p = PBB + (size_t)b * NB;
    if (l < NB) p[l] = base + i0 - v0;
    if (l + 64 < NB) p[l + 64] = base + t0 + i1 - v1;
}

__global__ __launch_bounds__(256) void binB(
    const int* __restrict__ src, const int* __restrict__ dst,
    int E, int CH, int NB, int nbk_c, int NBK,
    const int* __restrict__ PBB, unsigned* __restrict__ REC)
{
    __shared__ int fill[1024];
    const int blk = blockIdx.x, tid = threadIdx.x;
    for (int i = tid; i < NBK; i += 256) fill[i] = 0;
    __syncthreads();
    const int e0 = blk * CH, e1 = min(E, e0 + CH);
    for (int e = e0 + tid; e < e1; e += 256) {
        const int s = src[e], d = dst[e];
        const int bc = d >> 9;
        const int pc = PBB[bc * NB + blk] + atomicAdd(&fill[bc], 1);
        REC[pc] = (unsigned)s | ((unsigned)(d & 511) << 17);
        const int bp = nbk_c + (s >> 9);
        const int pp = PBB[bp * NB + blk] + atomicAdd(&fill[bp], 1);
        REC[pp] = (unsigned)d | ((unsigned)(s & 511) << 17);
    }
}

__global__ __launch_bounds__(256) void binC2(
    const unsigned* __restrict__ REC, const int* __restrict__ BB,
    int nbk_c, int NCn, int NPn,
    int* __restrict__ off_c, int* __restrict__ cnt_c,
    int* __restrict__ off_p, int* __restrict__ cnt_p, int* __restrict__ AJ)
{
    __shared__ int nh[512], lo[512], fl[512], ws2[4];
    const int b = blockIdx.x, tid = threadIdx.x;
    int Nn, node0;
    int *off_out, *cnt_out;
    if (b < nbk_c) { Nn = NCn; node0 = b << 9; off_out = off_c; cnt_out = cnt_c; }
    else { Nn = NPn; node0 = (b - nbk_c) << 9; off_out = off_p; cnt_out = cnt_p; }
    const int r0 = BB[b], r1 = BB[b + 1];
    const int kmax = min(512, Nn - node0);
    nh[tid] = 0; nh[tid + 256] = 0;
    fl[tid] = 0; fl[tid + 256] = 0;
    __syncthreads();
    for (int i = r0 + tid; i < r1; i += 256)
        atomicAdd(&nh[REC[i] >> 17], 1);
    __syncthreads();
    const int v0 = nh[2 * tid], v1 = nh[2 * tid + 1];
    const int s = v0 + v1;
    const int lane = tid & 63, wv = tid >> 6;
    int incl = s;
#pragma unroll
    for (int d = 1; d < 64; d <<= 1) {
        int up = __shfl_up(incl, d);
        if (lane >= d) incl += up;
    }
    if (lane == 63) ws2[wv] = incl;
    __syncthreads();
    if (tid == 0) {
        int run = 0;
        for (int w = 0; w < 4; ++w) { int t = ws2[w]; ws2[w] = run; run += t; }
    }
    __syncthreads();
    const int base = ws2[wv] + incl - s;
    lo[2 * tid] = base;
    lo[2 * tid + 1] = base + v0;
    __syncthreads();
    for (int k = tid; k < kmax; k += 256) {
        off_out[node0 + k] = r0 + lo[k];
        cnt_out[node0 + k] = nh[k];
    }
    for (int i = r0 + tid; i < r1; i += 256) {
        const unsigned rec = REC[i];
        const int k = rec >> 17;
        const int pos = r0 + lo[k] + atomicAdd(&fl[k], 1);
        AJ[pos] = (int)(rec & 0x1FFFFu);
    }
}

// ---- gather: Sdiv[n] = mean_e relu((RW[n]+LW[adj])*sf) ----
__global__ __launch_bounds__(256) void node_gather2(
    const int* __restrict__ off, const int* __restrict__ cnt,
    const int* __restrict__ adj,
    const u16* __restrict__ RW, const u16* __restrict__ LW,
    u16* __restrict__ Sdiv, float* __restrict__ cntf,
    const float* __restrict__ sf_p, int N)
{
    int t = blockIdx.x * 256 + threadIdx.x;
    int n = t >> 5;
    if (n >= N) return;
    int l32 = t & 31;
    int c = l32 & 15;
    int half = l32 >> 4;
    const float sf = *sf_p;
    const int start = off[n], len = cnt[n];

    float rw[8];
    unpack8(*(const uint4*)(RW + (size_t)n * 128 + c * 8), rw);
    float acc[8] = {0.f, 0.f, 0.f, 0.f, 0.f, 0.f, 0.f, 0.f};

    for (int i = half; i < len; i += 2) {
        int l = adj[start + i];
        float lw[8];
        unpack8(*(const uint4*)(LW + (size_t)l * 128 + c * 8), lw);
#pragma unroll
        for (int j = 0; j < 8; ++j)
            acc[j] += fmaxf((rw[j] + lw[j]) * sf, 0.f);
    }
#pragma unroll
    for (int j = 0; j < 8; ++j) acc[j] += __shfl_xor(acc[j], 16);

    if (half == 0) {
        float inv = 1.f / fmaxf((float)len, 1.f);
        uint4 o;
        o.x = pk2(acc[0] * inv, acc[1] * inv);
        o.y = pk2(acc[2] * inv, acc[3] * inv);
        o.z = pk2(acc[4] * inv, acc[5] * inv);
        o.w = pk2(acc[6] * inv, acc[7] * inv);
        *(uint4*)(Sdiv + (size_t)n * 128 + c * 8) = o;
        if (l32 == 0) cntf[n] = (float)len;
    }
}

extern "C" void kernel_launch(void* const* d_in, const int* in_sizes, int n_in,
                              void* d_out, int out_size, void* d_ws, size_t ws_size,
                              hipStream_t stream)
{
    const float* pivot = (const float*)d_in[0];
    const float* child = (const float*)d_in[1];
    const int* edges = (const int*)d_in[2];
    const int F = in_sizes[3];           // 69
    const int NP = in_sizes[0] / F;
    const int NC = in_sizes[1] / F;
    const int E = in_sizes[2] / 2;
    const int* src = edges;
    const int* dst = edges + E;

    const float *pe_shift = (const float*)d_in[3], *pe_scale = (const float*)d_in[4],
                *pe_w1 = (const float*)d_in[5], *pe_b1 = (const float*)d_in[6],
                *pe_w2 = (const float*)d_in[7], *pe_b2 = (const float*)d_in[8];
    const float *ce_shift = (const float*)d_in[9], *ce_scale = (const float*)d_in[10],
                *ce_w1 = (const float*)d_in[11], *ce_b1 = (const float*)d_in[12],
                *ce_w2 = (const float*)d_in[13], *ce_b2 = (const float*)d_in[14];
    const float *vc_wl = (const float*)d_in[15], *vc_bl = (const float*)d_in[16],
                *vc_wr = (const float*)d_in[17], *vc_sf = (const float*)d_in[18],
                *vc_wf = (const float*)d_in[19], *vc_bf = (const float*)d_in[20],
                *vc_sp = (const float*)d_in[21], *vc_wo1 = (const float*)d_in[22],
                *vc_bo1 = (const float*)d_in[23], *vc_wo2 = (const float*)d_in[24],
                *vc_bo2 = (const float*)d_in[25];
    const float *cv_wl = (const float*)d_in[26], *cv_bl = (const float*)d_in[27],
                *cv_wr = (const float*)d_in[28], *cv_sf = (const float*)d_in[29],
                *cv_wf = (const float*)d_in[30], *cv_bf = (const float*)d_in[31],
                *cv_sp = (const float*)d_in[32], *cv_wo1 = (const float*)d_in[33],
                *cv_bo1 = (const float*)d_in[34], *cv_wo2 = (const float*)d_in[35],
                *cv_bo2 = (const float*)d_in[36];
    const float *out_w1 = (const float*)d_in[37], *out_b1 = (const float*)d_in[38],
                *out_w2 = (const float*)d_in[39], *out_b2 = (const float*)d_in[40];

    // ---- workspace carve (256B aligned) ----
    char* base = (char*)d_ws;
    size_t off = 0;
    auto carve = [&](size_t bytes) {
        void* p = base + off;
        off += (bytes + 255) & ~(size_t)255;
        return p;
    };
    float* Wsc = (float*)carve((size_t)4 * 16384 * 4);
    float* Vsc = (float*)carve((size_t)4 * 128 * 4);
    u16* WT = (u16*)carve((size_t)14 * 32768 * 2);
    u16* FPC = (u16*)carve((size_t)(NP + NC) * 96 * 2);
    u16* FP = FPC;
    u16* FC = FPC + (size_t)NP * 96;
    u16* B0 = (u16*)carve((size_t)NP * 128 * 2);   // pv0
    u16* B1 = (u16*)carve((size_t)NC * 128 * 2);
    u16* B2 = (u16*)carve((size_t)NC * 128 * 2);   // ch0
    u16* B3 = (u16*)carve((size_t)NC * 128 * 2);   // LW_v -> LW_c
    u16* B4 = (u16*)carve((size_t)NC * 128 * 2);   // Sdiv
    u16* B5 = (u16*)carve((size_t)NC * 128 * 2);   // embed temp / h_c
    u16* B6 = (u16*)carve((size_t)NP * 128 * 2);   // RW_p
    const int NMAX = (NC > NP) ? NC : NP;
    float* cntf = (float*)carve((size_t)NMAX * 4);

    const int NB = 120;
    const int CH = (E + NB - 1) / NB;
    const int nbk_c = (NC + 511) >> 9;
    const int nbk_p = (NP + 511) >> 9;
    const int NBK = nbk_c + nbk_p;
    int* cnt_c = (int*)carve((size_t)NC * 4);
    int* cnt_p = (int*)carve((size_t)NP * 4);
    int* off_c = (int*)carve((size_t)NC * 4);
    int* off_p = (int*)carve((size_t)NP * 4);
    int* G = (int*)carve((size_t)NBK * NB * 4);
    int* PBB = (int*)carve((size_t)NBK * NB * 4);
    int* BB = (int*)carve((size_t)(NBK + 1) * 4);
    int* Tb = (int*)carve((size_t)NBK * 4);
    unsigned* REC = (unsigned*)carve((size_t)2 * E * 4);
    int* AJ = (int*)carve((size_t)2 * E * 4);

    // ---- folded weight precompute (fp32) ----
    SmPack sp;
    sp.e[0] = {vc_wf, vc_wo1, vc_sp};
    sp.e[1] = {cv_wf, cv_wo1, cv_sp};
    sp.e[2] = {vc_wo2, cv_wr, nullptr};
    sp.e[3] = {cv_wo2, out_w1, nullptr};
    hipLaunchKernelGGL(smallmm, dim3(256), dim3(256), 0, stream, sp, Wsc);
    hipLaunchKernelGGL(vecpre, dim3(1), dim3(128), 0, stream,
                       vc_bf, vc_wo1, vc_sp, cv_bf, cv_wo1, cv_sp,
                       vc_bo2, cv_wr, cv_bo2, out_w1, out_b1, Vsc);
    const float* cvec_vc = Vsc;
    const float* cvec_cv = Vsc + 128;
    const float* cx = Vsc + 256;
    const float* bh = Vsc + 384;

    // ---- weight conversion ----
    WPack wp;
    auto setw = [&](int i, const float* s, int ks, int kd) {
        wp.e[i].src = s; wp.e[i].Ksrc = ks; wp.e[i].Kdst = kd;
    };
    setw(0, pe_w1, F, 96);            setw(1, pe_w2, 128, 128);
    setw(2, ce_w1, F, 96);            setw(3, ce_w2, 128, 128);
    setw(4, vc_wl, 128, 128);         setw(5, vc_wr, 128, 128);
    setw(6, Wsc + 0 * 16384, 128, 128);
    setw(7, vc_wo1 + 128 * 128, 128, 128);
    setw(8, Wsc + 2 * 16384, 128, 128);
    setw(9, cv_wl, 128, 128);         setw(10, cv_wr, 128, 128);
    setw(11, Wsc + 1 * 16384, 128, 128);
    setw(12, cv_wo1 + 128 * 128, 128, 128);
    setw(13, Wsc + 3 * 16384, 128, 128);
    hipLaunchKernelGGL(wconvert, dim3(14 * 128), dim3(256), 0, stream, wp, WT);
    auto wt = [&](int i) { return WT + (size_t)i * 32768; };

    // ---- feature conversion (division-free, coalesced) ----
    hipLaunchKernelGGL(featconv3, dim3(2048), dim3(256), 0, stream,
                       pivot, child, pe_shift, pe_scale, ce_shift, ce_scale,
                       FPC, NP, NP + NC, F);

    // ---- CSR via counting sort ----
    hipMemsetAsync(Tb, 0, (size_t)NBK * 4, stream);
    hipLaunchKernelGGL(binA, dim3(NB), dim3(256), 0, stream,
                       src, dst, E, CH, NB, nbk_c, NBK, G, Tb);
    hipLaunchKernelGGL(binS, dim3(1), dim3(512), 0, stream, Tb, NBK, BB);
    hipLaunchKernelGGL(binP, dim3(NBK), dim3(64), 0, stream, G, BB, NB, PBB);
    hipLaunchKernelGGL(binB, dim3(NB), dim3(256), 0, stream,
                       src, dst, E, CH, NB, nbk_c, NBK, PBB, REC);
    hipLaunchKernelGGL(binC2, dim3(NBK), dim3(256), 0, stream,
                       REC, BB, nbk_c, NC, NP, off_c, cnt_c, off_p, cnt_p, AJ);

    // ---- GEMM pipeline ----
    const dim3 blk(256);
    auto grd = [](int M) {
        int items = M >> 4;
        int b = (items + 3) / 4;
        return dim3((unsigned)(b < 512 ? b : 512));
    };

    // embeddings layer 1 (batched): FP->B1 (NP), FC->B5 (NC)
    {
        GJobs3 j;
        j.j[0] = {FP, wt(0), pe_b1, B1, NP};
        j.j[1] = {FC, wt(2), ce_b1, B5, NC};
        j.j[2] = j.j[0];
        dim3 g = grd(NC); g.y = 2;
        hipLaunchKernelGGL(HIP_KERNEL_NAME(gemm_multi<3, true>), g, blk, 0, stream, j);
    }
    // embeddings layer 2 (batched): B1->B0 (pv0), B5->B2 (ch0)
    {
        GJobs3 j;
        j.j[0] = {B1, wt(1), pe_b2, B0, NP};
        j.j[1] = {B5, wt(3), ce_b2, B2, NC};
        j.j[2] = j.j[0];
        dim3 g = grd(NC); g.y = 2;
        hipLaunchKernelGGL(HIP_KERNEL_NAME(gemm_multi<4, true>), g, blk, 0, stream, j);
    }
    // RW_c / LW_v / RW_p (batched)
    {
        GJobs3 j;
        j.j[0] = {B2, wt(4), vc_bl, B1, NC};    // RW_c = ch0@wl+bl
        j.j[1] = {B0, wt(5), nullptr, B3, NP};  // LW_v = pv0@wr
        j.j[2] = {B0, wt(9), cv_bl, B6, NP};    // RW_p = pv0@cv_wl+bl
        dim3 g = grd(NC); g.y = 3;
        hipLaunchKernelGGL(HIP_KERNEL_NAME(gemm_multi<4, false>), g, blk, 0, stream, j);
    }

    // conv v->c
    hipLaunchKernelGGL(node_gather2, dim3(((size_t)NC * 32 + 255) / 256), blk, 0,
                       stream, off_c, cnt_c, AJ, B1, B3, B4, cntf, vc_sf, NC);
    gemm_rb<4, true, true, true><<<grd(NC), blk, 0, stream>>>(
        B4, B2, wt(6), wt(7), vc_bo1, cvec_vc, cntf, B5, NC);            // h_c
    gemm_rb<4, false, false, false><<<grd(NC), blk, 0, stream>>>(
        B5, nullptr, wt(8), nullptr, cx, nullptr, nullptr, B3, NC);      // LW_c

    // conv c->v
    hipLaunchKernelGGL(node_gather2, dim3(((size_t)NP * 32 + 255) / 256), blk, 0,
                       stream, off_p, cnt_p, AJ, B6, B3, B4, cntf, cv_sf, NP);
    gemm_rb<4, true, true, true><<<grd(NP), blk, 0, stream>>>(
        B4, B0, wt(11), wt(12), cv_bo1, cvec_cv, cntf, B1, NP);          // h_p

    // head on h_p with folded W1'=Wh, b1'=bh
    hipLaunchKernelGGL(head_fused, grd(NP), blk, 0, stream,
                       B1, wt(13), bh, out_w2, out_b2, (float*)d_out, NP);
}

// Round 16
// 328.265 us; speedup vs baseline: 1.3198x; 1.0060x over previous
//
#include <hip/hip_runtime.h>
#include <math.h>

// ---------------------------------------------------------------------------
// Round 16: r15 (best, 330us) + r14's proven LDS-bounce coalesced-store
// epilogue applied to gemm_rb (h_c / h_p / LW_c passes were still using the
// scattered-2B-store epilogue that r14 fixed in gemm_multi).
// Everything else byte-identical to r15.
// ---------------------------------------------------------------------------

typedef unsigned short u16;
typedef __attribute__((ext_vector_type(8))) short s8v;   // 8 bf16 = 4 VGPR
typedef __attribute__((ext_vector_type(4))) float f4v;   // MFMA C/D frag

__device__ __forceinline__ float bf2f(u16 u) {
    unsigned x = ((unsigned)u) << 16;
    return __builtin_bit_cast(float, x);
}
__device__ __forceinline__ u16 f2bf(float f) {
    unsigned x = __builtin_bit_cast(unsigned, f);
    unsigned r = x + 0x7fffu + ((x >> 16) & 1u);
    return (u16)(r >> 16);
}
__device__ __forceinline__ unsigned pk2(float a, float b) {
    return (unsigned)f2bf(a) | ((unsigned)f2bf(b) << 16);
}
__device__ __forceinline__ void unpack8(uint4 u, float* f) {
    f[0] = bf2f((u16)(u.x & 0xffff)); f[1] = bf2f((u16)(u.x >> 16));
    f[2] = bf2f((u16)(u.y & 0xffff)); f[3] = bf2f((u16)(u.y >> 16));
    f[4] = bf2f((u16)(u.z & 0xffff)); f[5] = bf2f((u16)(u.z >> 16));
    f[6] = bf2f((u16)(u.w & 0xffff)); f[7] = bf2f((u16)(u.w >> 16));
}

// ---- small fp32 128x128 matmuls for folded weights ----
struct SmEnt { const float* A; const float* B; const float* s; };
struct SmPack { SmEnt e[4]; };

__global__ __launch_bounds__(256) void smallmm(SmPack p, float* __restrict__ out)
{
    int t = blockIdx.x * 256 + threadIdx.x;
    int m = t >> 14;
    int o = t & 16383;
    int i = o >> 7, j = o & 127;
    SmEnt en = p.e[m];
    float acc = 0.f;
#pragma unroll 4
    for (int k = 0; k < 128; ++k) acc += en.A[i * 128 + k] * en.B[k * 128 + j];
    if (en.s) acc *= *en.s;
    out[(size_t)m * 16384 + o] = acc;
}

__global__ void vecpre(
    const float* vc_bf, const float* vc_wo1, const float* vc_sp,
    const float* cv_bf, const float* cv_wo1, const float* cv_sp,
    const float* vc_bo2, const float* cv_wr,
    const float* cv_bo2, const float* out_w1, const float* out_b1,
    float* __restrict__ vout)
{
    int j = threadIdx.x;
    if (j >= 128) return;
    float a0 = 0.f, a1 = 0.f, a2 = 0.f, a3 = 0.f;
    for (int k = 0; k < 128; ++k) {
        a0 += vc_bf[k] * vc_wo1[k * 128 + j];
        a1 += cv_bf[k] * cv_wo1[k * 128 + j];
        a2 += vc_bo2[k] * cv_wr[k * 128 + j];
        a3 += cv_bo2[k] * out_w1[k * 128 + j];
    }
    vout[j] = a0 * (*vc_sp);
    vout[128 + j] = a1 * (*cv_sp);
    vout[256 + j] = a2;
    vout[384 + j] = a3 + out_b1[j];
}

// ---- weight conversion: fp32 [Ksrc][128] -> bf16 WT[col*Kdst + k], pad k ----
struct WEnt { const float* src; int Ksrc; int Kdst; };
struct WPack { WEnt e[14]; };

__global__ __launch_bounds__(256) void wconvert(WPack p, u16* __restrict__ wt)
{
    int t = blockIdx.x * 256 + threadIdx.x;
    int m = t >> 15;
    int i = t & 32767;
    WEnt en = p.e[m];
    if (i >= (en.Kdst << 7)) return;
    int k = i >> 7, col = i & 127;
    float v = (k < en.Ksrc) ? en.src[k * 128 + col] : 0.f;
    wt[(size_t)m * 32768 + (size_t)col * en.Kdst + k] = f2bf(v);
}

// ---- feature conversion: division-free, coalesced ----
__global__ __launch_bounds__(256) void featconv3(
    const float* __restrict__ pv, const float* __restrict__ ch,
    const float* __restrict__ psh, const float* __restrict__ psc,
    const float* __restrict__ csh, const float* __restrict__ csc,
    u16* __restrict__ y, int NPr, int NTOT, int F)
{
    const int l = threadIdx.x & 31;
    const int rl = threadIdx.x >> 5;
    for (int row = blockIdx.x * 8 + rl; row < NTOT; row += gridDim.x * 8) {
        const float *x, *sh, *sc;
        int r;
        if (row < NPr) { x = pv; sh = psh; sc = psc; r = row; }
        else { x = ch; sh = csh; sc = csc; r = row - NPr; }
        const float* xr = x + (size_t)r * F;
        u16* yr = y + (size_t)row * 96;
#pragma unroll
        for (int k = 0; k < 3; ++k) {
            const int cc = l + k * 32;
            float v = 0.f;
            if (cc < F) v = (xr[cc] + sh[cc]) * sc[cc];
            yr[cc] = f2bf(v);
        }
    }
}

// ---- register-persistent-B GEMM + LDS-bounce coalesced store epilogue ----
template <int KS1, bool HASA2, bool RELU, bool GATE>
__global__ __launch_bounds__(256) void gemm_rb(
    const u16* __restrict__ A1, const u16* __restrict__ A2,
    const u16* __restrict__ WT1,     // bf16 [128][KS1*32]
    const u16* __restrict__ WT2,     // bf16 [128][128] (when HASA2)
    const float* __restrict__ bias0, // fp32 [128] or null
    const float* __restrict__ bias1, // fp32 [128] or null (gated)
    const float* __restrict__ gate,  // fp32 [M] (cnt) when GATE
    u16* __restrict__ out, int M)    // M % 16 == 0
{
    constexpr int K1 = KS1 * 32;
    constexpr bool PF = !HASA2;
    constexpr int AS = KS1 + (HASA2 ? 4 : 0);
    __shared__ u16 tile[4][16 * 136];
    const int lane = threadIdx.x & 63;
    const int c = lane & 15;
    const int kg = lane >> 4;
    const int wv = threadIdx.x >> 6;
    const int wid = blockIdx.x * 4 + wv;
    const int ws = gridDim.x * 4;
    const int items = M >> 4;
    u16* tl = tile[wv];

    const u16* wbase = WT1 + (size_t)c * K1 + kg * 8;
    s8v bp[KS1][8];
#pragma unroll
    for (int ks = 0; ks < KS1; ++ks)
#pragma unroll
        for (int nt = 0; nt < 8; ++nt)
            bp[ks][nt] = *(const s8v*)(wbase + ((size_t)nt * 16) * K1 + ks * 32);

    const u16* wbase2 = HASA2 ? (WT2 + (size_t)c * 128 + kg * 8) : nullptr;

    float bc0[8], bc1[8];
#pragma unroll
    for (int nt = 0; nt < 8; ++nt) {
        bc0[nt] = bias0 ? bias0[nt * 16 + c] : 0.f;
        bc1[nt] = (GATE && bias1) ? bias1[nt * 16 + c] : 0.f;
    }

    auto lda = [&](s8v* a, int item) {
        const u16* ap = A1 + (size_t)((item << 4) + c) * K1 + kg * 8;
#pragma unroll
        for (int ks = 0; ks < KS1; ++ks) a[ks] = *(const s8v*)(ap + ks * 32);
        if (HASA2) {
            const u16* ap2 = A2 + (size_t)((item << 4) + c) * 128 + kg * 8;
#pragma unroll
            for (int ks = 0; ks < 4; ++ks) a[KS1 + ks] = *(const s8v*)(ap2 + ks * 32);
        }
    };

    s8v a[AS], an[AS], a2[AS];
    int item = wid;
    if (item < items) lda(a, item);
    if (PF && item + ws < items) lda(an, item + ws);
    while (item < items) {
        const int i2 = item + 2 * ws;
        if (PF && i2 < items) lda(a2, i2);

        f4v acc[8];
#pragma unroll
        for (int nt = 0; nt < 8; ++nt) acc[nt] = (f4v){0.f, 0.f, 0.f, 0.f};
#pragma unroll
        for (int ks = 0; ks < KS1; ++ks)
#pragma unroll
            for (int nt = 0; nt < 8; ++nt)
                acc[nt] = __builtin_amdgcn_mfma_f32_16x16x32_bf16(a[ks], bp[ks][nt], acc[nt], 0, 0, 0);
        if (HASA2) {
#pragma unroll
            for (int ks = 0; ks < 4; ++ks)
#pragma unroll
                for (int nt = 0; nt < 8; ++nt) {
                    s8v b = *(const s8v*)(wbase2 + ((size_t)nt * 16) * 128 + ks * 32);
                    acc[nt] = __builtin_amdgcn_mfma_f32_16x16x32_bf16(a[KS1 + ks], b, acc[nt], 0, 0, 0);
                }
        }

        const int r0 = item << 4;
        float g4[4];
#pragma unroll
        for (int j = 0; j < 4; ++j)
            g4[j] = GATE ? (gate[r0 + kg * 4 + j] > 0.f ? 1.f : 0.f) : 0.f;
        // stage to wave-private LDS tile (wave-ordered, no barrier)
#pragma unroll
        for (int nt = 0; nt < 8; ++nt)
#pragma unroll
            for (int j = 0; j < 4; ++j) {
                float v = acc[nt][j] + bc0[nt] + g4[j] * bc1[nt];
                if (RELU) v = fmaxf(v, 0.f);
                tl[(kg * 4 + j) * 136 + nt * 16 + c] = f2bf(v);
            }
        // 4 coalesced 1KB stores
#pragma unroll
        for (int k = 0; k < 4; ++k) {
            const int f = k * 512 + lane * 8;
            const int row = f >> 7, col = f & 127;
            uint4 v = *(const uint4*)&tl[row * 136 + col];
            *(uint4*)&out[(size_t)r0 * 128 + f] = v;
        }

        if (PF) {
#pragma unroll
            for (int ks = 0; ks < AS; ++ks) { a[ks] = an[ks]; an[ks] = a2[ks]; }
        } else if (item + ws < items) {
            lda(a, item + ws);
        }
        item += ws;
    }
}

// ---- multi-job GEMM: r14 (LDS-bounce coalesced store epilogue) ----
struct GJob { const u16* A1; const u16* WT1; const float* bias0; u16* out; int M; };
struct GJobs3 { GJob j[3]; };

template <int KS1, bool RELU>
__global__ __launch_bounds__(256) void gemm_multi(GJobs3 jobs)
{
    constexpr int K1 = KS1 * 32;
    __shared__ u16 tile[4][16 * 136];
    const GJob jb = jobs.j[blockIdx.y];
    const u16* __restrict__ A1 = jb.A1;
    const float* __restrict__ bias0 = jb.bias0;
    u16* __restrict__ out = jb.out;
    const int lane = threadIdx.x & 63;
    const int c = lane & 15;
    const int kg = lane >> 4;
    const int wv = threadIdx.x >> 6;
    const int wid = blockIdx.x * 4 + wv;
    const int ws = gridDim.x * 4;
    const int items = jb.M >> 4;
    u16* tl = tile[wv];

    const u16* wbase = jb.WT1 + (size_t)c * K1 + kg * 8;
    s8v bp[KS1][8];
#pragma unroll
    for (int ks = 0; ks < KS1; ++ks)
#pragma unroll
        for (int nt = 0; nt < 8; ++nt)
            bp[ks][nt] = *(const s8v*)(wbase + ((size_t)nt * 16) * K1 + ks * 32);

    float bc0[8];
#pragma unroll
    for (int nt = 0; nt < 8; ++nt)
        bc0[nt] = bias0 ? bias0[nt * 16 + c] : 0.f;

    auto lda = [&](s8v* a, int item) {
        const u16* ap = A1 + (size_t)((item << 4) + c) * K1 + kg * 8;
#pragma unroll
        for (int ks = 0; ks < KS1; ++ks) a[ks] = *(const s8v*)(ap + ks * 32);
    };

    s8v a[KS1], an[KS1], a2[KS1];
    int item = wid;
    if (item < items) lda(a, item);
    if (item + ws < items) lda(an, item + ws);
    while (item < items) {
        const int i2 = item + 2 * ws;
        if (i2 < items) lda(a2, i2);

        f4v acc[8];
#pragma unroll
        for (int nt = 0; nt < 8; ++nt) acc[nt] = (f4v){0.f, 0.f, 0.f, 0.f};
#pragma unroll
        for (int ks = 0; ks < KS1; ++ks)
#pragma unroll
            for (int nt = 0; nt < 8; ++nt)
                acc[nt] = __builtin_amdgcn_mfma_f32_16x16x32_bf16(a[ks], bp[ks][nt], acc[nt], 0, 0, 0);

        const int r0 = item << 4;
#pragma unroll
        for (int nt = 0; nt < 8; ++nt)
#pragma unroll
            for (int j = 0; j < 4; ++j) {
                float v = acc[nt][j] + bc0[nt];
                if (RELU) v = fmaxf(v, 0.f);
                tl[(kg * 4 + j) * 136 + nt * 16 + c] = f2bf(v);
            }
#pragma unroll
        for (int k = 0; k < 4; ++k) {
            const int f = k * 512 + lane * 8;
            const int row = f >> 7, col = f & 127;
            uint4 v = *(const uint4*)&tl[row * 136 + col];
            *(uint4*)&out[(size_t)r0 * 128 + f] = v;
        }

#pragma unroll
        for (int ks = 0; ks < KS1; ++ks) { a[ks] = an[ks]; an[ks] = a2[ks]; }
        item += ws;
    }
}

// ---- fused head: sigmoid(relu(A@W1+b1) @ w2 + b2) -> [M,2] fp32 ----
__global__ __launch_bounds__(256) void head_fused(
    const u16* __restrict__ A1, const u16* __restrict__ WT,
    const float* __restrict__ b1, const float* __restrict__ w2,
    const float* __restrict__ b2, float* __restrict__ outp, int M)
{
    constexpr int KT = 128;
    const int lane = threadIdx.x & 63;
    const int c = lane & 15;
    const int kg = lane >> 4;
    const int wid = blockIdx.x * 4 + (threadIdx.x >> 6);
    const int ws = gridDim.x * 4;
    const int items = M >> 4;

    const u16* wbase = WT + (size_t)c * KT + kg * 8;
    s8v bp[4][8];
#pragma unroll
    for (int ks = 0; ks < 4; ++ks)
#pragma unroll
        for (int nt = 0; nt < 8; ++nt)
            bp[ks][nt] = *(const s8v*)(wbase + ((size_t)nt * 16) * KT + ks * 32);

    float bc[8], w2c0[8], w2c1[8];
#pragma unroll
    for (int nt = 0; nt < 8; ++nt) {
        int col = nt * 16 + c;
        bc[nt] = b1[col];
        w2c0[nt] = w2[col * 2 + 0];
        w2c1[nt] = w2[col * 2 + 1];
    }
    const float s0 = b2[0], s1 = b2[1];

    for (int item = wid; item < items; item += ws) {
        const int r0 = item << 4;
        const u16* ap = A1 + (size_t)(r0 + c) * 128 + kg * 8;
        s8v a[4];
#pragma unroll
        for (int ks = 0; ks < 4; ++ks) a[ks] = *(const s8v*)(ap + ks * 32);

        f4v acc[8];
#pragma unroll
        for (int nt = 0; nt < 8; ++nt) acc[nt] = (f4v){0.f, 0.f, 0.f, 0.f};
#pragma unroll
        for (int ks = 0; ks < 4; ++ks)
#pragma unroll
            for (int nt = 0; nt < 8; ++nt)
                acc[nt] = __builtin_amdgcn_mfma_f32_16x16x32_bf16(a[ks], bp[ks][nt], acc[nt], 0, 0, 0);

        float pp0[4] = {0.f, 0.f, 0.f, 0.f}, pp1[4] = {0.f, 0.f, 0.f, 0.f};
#pragma unroll
        for (int nt = 0; nt < 8; ++nt)
#pragma unroll
            for (int j = 0; j < 4; ++j) {
                float v = fmaxf(acc[nt][j] + bc[nt], 0.f);
                pp0[j] += v * w2c0[nt];
                pp1[j] += v * w2c1[nt];
            }
#pragma unroll
        for (int m = 1; m < 16; m <<= 1)
#pragma unroll
            for (int j = 0; j < 4; ++j) {
                pp0[j] += __shfl_xor(pp0[j], m);
                pp1[j] += __shfl_xor(pp1[j], m);
            }
        if (c == 0) {
#pragma unroll
            for (int j = 0; j < 4; ++j) {
                int row = r0 + kg * 4 + j;
                outp[(size_t)row * 2 + 0] = 1.f / (1.f + expf(-(pp0[j] + s0)));
                outp[(size_t)row * 2 + 1] = 1.f / (1.f + expf(-(pp1[j] + s1)));
            }
        }
    }
}

// ============================ CSR counting sort ============================
__global__ __launch_bounds__(256) void binA(
    const int* __restrict__ src, const int* __restrict__ dst,
    int E, int CH, int NB, int nbk_c, int NBK,
    int* __restrict__ G, int* __restrict__ Tb)
{
    __shared__ int h[1024];
    const int blk = blockIdx.x, tid = threadIdx.x;
    for (int i = tid; i < NBK; i += 256) h[i] = 0;
    __syncthreads();
    const int e0 = blk * CH, e1 = min(E, e0 + CH);
    for (int e = e0 + tid; e < e1; e += 256) {
        atomicAdd(&h[dst[e] >> 9], 1);
        atomicAdd(&h[nbk_c + (src[e] >> 9)], 1);
    }
    __syncthreads();
    for (int b = tid; b < NBK; b += 256) {
        const int v = h[b];
        G[b * NB + blk] = v;
        if (v) atomicAdd(&Tb[b], v);
    }
}

__global__ __launch_bounds__(512) void binS(
    const int* __restrict__ Tb, int NBK, int* __restrict__ BB)
{
    __shared__ int wsum[8];
    const int tid = threadIdx.x;
    const int T = (tid < NBK) ? Tb[tid] : 0;
    const int lane = tid & 63, wv = tid >> 6;
    int incl = T;
#pragma unroll
    for (int d = 1; d < 64; d <<= 1) {
        int up = __shfl_up(incl, d);
        if (lane >= d) incl += up;
    }
    if (lane == 63) wsum[wv] = incl;
    __syncthreads();
    if (tid == 0) {
        int run = 0;
        for (int w = 0; w < 8; ++w) { int t = wsum[w]; wsum[w] = run; run += t; }
    }
    __syncthreads();
    const int base = wsum[wv] + incl - T;
    if (tid < NBK) {
        BB[tid] = base;
        if (tid == NBK - 1) BB[NBK] = base + T;
    }
}

__global__ __launch_bounds__(64) void binP(
    const int* __restrict__ G, const int* __restrict__ BB,
    int NB, int* __restrict__ PBB)
{
    const int b = blockIdx.x, l = threadIdx.x;
    const int* g = G + (size_t)b * NB;
    const int v0 = (l < NB) ? g[l] : 0;
    const int v1 = (l + 64 < NB) ? g[l + 64] : 0;
    int i0 = v0, i1 = v1;
#pragma unroll
    for (int d = 1; d < 64; d <<= 1) {
        int u0 = __shfl_up(i0, d);
        int u1 = __shfl_up(i1, d);
        if (l >= d) { i0 += u0; i1 += u1; }
    }
    const int t0 = __shfl(i0, 63);
    const int base = BB[b];
    int* p = PBB + (size_t)b * NB;
    if (l < NB) p[l] = base + i0 - v0;
    if (l + 64 < NB) p[l + 64] = base + t0 + i1 - v1;
}

__global__ __launch_bounds__(256) void binB(
    const int* __restrict__ src, const int* __restrict__ dst,
    int E, int CH, int NB, int nbk_c, int NBK,
    const int* __restrict__ PBB, unsigned* __restrict__ REC)
{
    __shared__ int fill[1024];
    const int blk = blockIdx.x, tid = threadIdx.x;
    for (int i = tid; i < NBK; i += 256) fill[i] = 0;
    __syncthreads();
    const int e0 = blk * CH, e1 = min(E, e0 + CH);
    for (int e = e0 + tid; e < e1; e += 256) {
        const int s = src[e], d = dst[e];
        const int bc = d >> 9;
        const int pc = PBB[bc * NB + blk] + atomicAdd(&fill[bc], 1);
        REC[pc] = (unsigned)s | ((unsigned)(d & 511) << 17);
        const int bp = nbk_c + (s >> 9);
        const int pp = PBB[bp * NB + blk] + atomicAdd(&fill[bp], 1);
        REC[pp] = (unsigned)d | ((unsigned)(s & 511) << 17);
    }
}

__global__ __launch_bounds__(256) void binC2(
    const unsigned* __restrict__ REC, const int* __restrict__ BB,
    int nbk_c, int NCn, int NPn,
    int* __restrict__ off_c, int* __restrict__ cnt_c,
    int* __restrict__ off_p, int* __restrict__ cnt_p, int* __restrict__ AJ)
{
    __shared__ int nh[512], lo[512], fl[512], ws2[4];
    const int b = blockIdx.x, tid = threadIdx.x;
    int Nn, node0;
    int *off_out, *cnt_out;
    if (b < nbk_c) { Nn = NCn; node0 = b << 9; off_out = off_c; cnt_out = cnt_c; }
    else { Nn = NPn; node0 = (b - nbk_c) << 9; off_out = off_p; cnt_out = cnt_p; }
    const int r0 = BB[b], r1 = BB[b + 1];
    const int kmax = min(512, Nn - node0);
    nh[tid] = 0; nh[tid + 256] = 0;
    fl[tid] = 0; fl[tid + 256] = 0;
    __syncthreads();
    for (int i = r0 + tid; i < r1; i += 256)
        atomicAdd(&nh[REC[i] >> 17], 1);
    __syncthreads();
    const int v0 = nh[2 * tid], v1 = nh[2 * tid + 1];
    const int s = v0 + v1;
    const int lane = tid & 63, wv = tid >> 6;
    int incl = s;
#pragma unroll
    for (int d = 1; d < 64; d <<= 1) {
        int up = __shfl_up(incl, d);
        if (lane >= d) incl += up;
    }
    if (lane == 63) ws2[wv] = incl;
    __syncthreads();
    if (tid == 0) {
        int run = 0;
        for (int w = 0; w < 4; ++w) { int t = ws2[w]; ws2[w] = run; run += t; }
    }
    __syncthreads();
    const int base = ws2[wv] + incl - s;
    lo[2 * tid] = base;
    lo[2 * tid + 1] = base + v0;
    __syncthreads();
    for (int k = tid; k < kmax; k += 256) {
        off_out[node0 + k] = r0 + lo[k];
        cnt_out[node0 + k] = nh[k];
    }
    for (int i = r0 + tid; i < r1; i += 256) {
        const unsigned rec = REC[i];
        const int k = rec >> 17;
        const int pos = r0 + lo[k] + atomicAdd(&fl[k], 1);
        AJ[pos] = (int)(rec & 0x1FFFFu);
    }
}

// ---- gather: Sdiv[n] = mean_e relu((RW[n]+LW[adj])*sf) ----
__global__ __launch_bounds__(256) void node_gather2(
    const int* __restrict__ off, const int* __restrict__ cnt,
    const int* __restrict__ adj,
    const u16* __restrict__ RW, const u16* __restrict__ LW,
    u16* __restrict__ Sdiv, float* __restrict__ cntf,
    const float* __restrict__ sf_p, int N)
{
    int t = blockIdx.x * 256 + threadIdx.x;
    int n = t >> 5;
    if (n >= N) return;
    int l32 = t & 31;
    int c = l32 & 15;
    int half = l32 >> 4;
    const float sf = *sf_p;
    const int start = off[n], len = cnt[n];

    float rw[8];
    unpack8(*(const uint4*)(RW + (size_t)n * 128 + c * 8), rw);
    float acc[8] = {0.f, 0.f, 0.f, 0.f, 0.f, 0.f, 0.f, 0.f};

    for (int i = half; i < len; i += 2) {
        int l = adj[start + i];
        float lw[8];
        unpack8(*(const uint4*)(LW + (size_t)l * 128 + c * 8), lw);
#pragma unroll
        for (int j = 0; j < 8; ++j)
            acc[j] += fmaxf((rw[j] + lw[j]) * sf, 0.f);
    }
#pragma unroll
    for (int j = 0; j < 8; ++j) acc[j] += __shfl_xor(acc[j], 16);

    if (half == 0) {
        float inv = 1.f / fmaxf((float)len, 1.f);
        uint4 o;
        o.x = pk2(acc[0] * inv, acc[1] * inv);
        o.y = pk2(acc[2] * inv, acc[3] * inv);
        o.z = pk2(acc[4] * inv, acc[5] * inv);
        o.w = pk2(acc[6] * inv, acc[7] * inv);
        *(uint4*)(Sdiv + (size_t)n * 128 + c * 8) = o;
        if (l32 == 0) cntf[n] = (float)len;
    }
}

extern "C" void kernel_launch(void* const* d_in, const int* in_sizes, int n_in,
                              void* d_out, int out_size, void* d_ws, size_t ws_size,
                              hipStream_t stream)
{
    const float* pivot = (const float*)d_in[0];
    const float* child = (const float*)d_in[1];
    const int* edges = (const int*)d_in[2];
    const int F = in_sizes[3];           // 69
    const int NP = in_sizes[0] / F;
    const int NC = in_sizes[1] / F;
    const int E = in_sizes[2] / 2;
    const int* src = edges;
    const int* dst = edges + E;

    const float *pe_shift = (const float*)d_in[3], *pe_scale = (const float*)d_in[4],
                *pe_w1 = (const float*)d_in[5], *pe_b1 = (const float*)d_in[6],
                *pe_w2 = (const float*)d_in[7], *pe_b2 = (const float*)d_in[8];
    const float *ce_shift = (const float*)d_in[9], *ce_scale = (const float*)d_in[10],
                *ce_w1 = (const float*)d_in[11], *ce_b1 = (const float*)d_in[12],
                *ce_w2 = (const float*)d_in[13], *ce_b2 = (const float*)d_in[14];
    const float *vc_wl = (const float*)d_in[15], *vc_bl = (const float*)d_in[16],
                *vc_wr = (const float*)d_in[17], *vc_sf = (const float*)d_in[18],
                *vc_wf = (const float*)d_in[19], *vc_bf = (const float*)d_in[20],
                *vc_sp = (const float*)d_in[21], *vc_wo1 = (const float*)d_in[22],
                *vc_bo1 = (const float*)d_in[23], *vc_wo2 = (const float*)d_in[24],
                *vc_bo2 = (const float*)d_in[25];
    const float *cv_wl = (const float*)d_in[26], *cv_bl = (const float*)d_in[27],
                *cv_wr = (const float*)d_in[28], *cv_sf = (const float*)d_in[29],
                *cv_wf = (const float*)d_in[30], *cv_bf = (const float*)d_in[31],
                *cv_sp = (const float*)d_in[32], *cv_wo1 = (const float*)d_in[33],
                *cv_bo1 = (const float*)d_in[34], *cv_wo2 = (const float*)d_in[35],
                *cv_bo2 = (const float*)d_in[36];
    const float *out_w1 = (const float*)d_in[37], *out_b1 = (const float*)d_in[38],
                *out_w2 = (const float*)d_in[39], *out_b2 = (const float*)d_in[40];

    // ---- workspace carve (256B aligned) ----
    char* base = (char*)d_ws;
    size_t off = 0;
    auto carve = [&](size_t bytes) {
        void* p = base + off;
        off += (bytes + 255) & ~(size_t)255;
        return p;
    };
    float* Wsc = (float*)carve((size_t)4 * 16384 * 4);
    float* Vsc = (float*)carve((size_t)4 * 128 * 4);
    u16* WT = (u16*)carve((size_t)14 * 32768 * 2);
    u16* FPC = (u16*)carve((size_t)(NP + NC) * 96 * 2);
    u16* FP = FPC;
    u16* FC = FPC + (size_t)NP * 96;
    u16* B0 = (u16*)carve((size_t)NP * 128 * 2);   // pv0
    u16* B1 = (u16*)carve((size_t)NC * 128 * 2);
    u16* B2 = (u16*)carve((size_t)NC * 128 * 2);   // ch0
    u16* B3 = (u16*)carve((size_t)NC * 128 * 2);   // LW_v -> LW_c
    u16* B4 = (u16*)carve((size_t)NC * 128 * 2);   // Sdiv
    u16* B5 = (u16*)carve((size_t)NC * 128 * 2);   // embed temp / h_c
    u16* B6 = (u16*)carve((size_t)NP * 128 * 2);   // RW_p
    const int NMAX = (NC > NP) ? NC : NP;
    float* cntf = (float*)carve((size_t)NMAX * 4);

    const int NB = 120;
    const int CH = (E + NB - 1) / NB;
    const int nbk_c = (NC + 511) >> 9;
    const int nbk_p = (NP + 511) >> 9;
    const int NBK = nbk_c + nbk_p;
    int* cnt_c = (int*)carve((size_t)NC * 4);
    int* cnt_p = (int*)carve((size_t)NP * 4);
    int* off_c = (int*)carve((size_t)NC * 4);
    int* off_p = (int*)carve((size_t)NP * 4);
    int* G = (int*)carve((size_t)NBK * NB * 4);
    int* PBB = (int*)carve((size_t)NBK * NB * 4);
    int* BB = (int*)carve((size_t)(NBK + 1) * 4);
    int* Tb = (int*)carve((size_t)NBK * 4);
    unsigned* REC = (unsigned*)carve((size_t)2 * E * 4);
    int* AJ = (int*)carve((size_t)2 * E * 4);

    // ---- folded weight precompute (fp32) ----
    SmPack sp;
    sp.e[0] = {vc_wf, vc_wo1, vc_sp};
    sp.e[1] = {cv_wf, cv_wo1, cv_sp};
    sp.e[2] = {vc_wo2, cv_wr, nullptr};
    sp.e[3] = {cv_wo2, out_w1, nullptr};
    hipLaunchKernelGGL(smallmm, dim3(256), dim3(256), 0, stream, sp, Wsc);
    hipLaunchKernelGGL(vecpre, dim3(1), dim3(128), 0, stream,
                       vc_bf, vc_wo1, vc_sp, cv_bf, cv_wo1, cv_sp,
                       vc_bo2, cv_wr, cv_bo2, out_w1, out_b1, Vsc);
    const float* cvec_vc = Vsc;
    const float* cvec_cv = Vsc + 128;
    const float* cx = Vsc + 256;
    const float* bh = Vsc + 384;

    // ---- weight conversion ----
    WPack wp;
    auto setw = [&](int i, const float* s, int ks, int kd) {
        wp.e[i].src = s; wp.e[i].Ksrc = ks; wp.e[i].Kdst = kd;
    };
    setw(0, pe_w1, F, 96);            setw(1, pe_w2, 128, 128);
    setw(2, ce_w1, F, 96);            setw(3, ce_w2, 128, 128);
    setw(4, vc_wl, 128, 128);         setw(5, vc_wr, 128, 128);
    setw(6, Wsc + 0 * 16384, 128, 128);
    setw(7, vc_wo1 + 128 * 128, 128, 128);
    setw(8, Wsc + 2 * 16384, 128, 128);
    setw(9, cv_wl, 128, 128);         setw(10, cv_wr, 128, 128);
    setw(11, Wsc + 1 * 16384, 128, 128);
    setw(12, cv_wo1 + 128 * 128, 128, 128);
    setw(13, Wsc + 3 * 16384, 128, 128);
    hipLaunchKernelGGL(wconvert, dim3(14 * 128), dim3(256), 0, stream, wp, WT);
    auto wt = [&](int i) { return WT + (size_t)i * 32768; };

    // ---- feature conversion (division-free, coalesced) ----
    hipLaunchKernelGGL(featconv3, dim3(2048), dim3(256), 0, stream,
                       pivot, child, pe_shift, pe_scale, ce_shift, ce_scale,
                       FPC, NP, NP + NC, F);

    // ---- CSR via counting sort ----
    hipMemsetAsync(Tb, 0, (size_t)NBK * 4, stream);
    hipLaunchKernelGGL(binA, dim3(NB), dim3(256), 0, stream,
                       src, dst, E, CH, NB, nbk_c, NBK, G, Tb);
    hipLaunchKernelGGL(binS, dim3(1), dim3(512), 0, stream, Tb, NBK, BB);
    hipLaunchKernelGGL(binP, dim3(NBK), dim3(64), 0, stream, G, BB, NB, PBB);
    hipLaunchKernelGGL(binB, dim3(NB), dim3(256), 0, stream,
                       src, dst, E, CH, NB, nbk_c, NBK, PBB, REC);
    hipLaunchKernelGGL(binC2, dim3(NBK), dim3(256), 0, stream,
                       REC, BB, nbk_c, NC, NP, off_c, cnt_c, off_p, cnt_p, AJ);

    // ---- GEMM pipeline ----
    const dim3 blk(256);
    auto grd = [](int M) {
        int items = M >> 4;
        int b = (items + 3) / 4;
        return dim3((unsigned)(b < 512 ? b : 512));
    };

    // embeddings layer 1 (batched): FP->B1 (NP), FC->B5 (NC)
    {
        GJobs3 j;
        j.j[0] = {FP, wt(0), pe_b1, B1, NP};
        j.j[1] = {FC, wt(2), ce_b1, B5, NC};
        j.j[2] = j.j[0];
        dim3 g = grd(NC); g.y = 2;
        hipLaunchKernelGGL(HIP_KERNEL_NAME(gemm_multi<3, true>), g, blk, 0, stream, j);
    }
    // embeddings layer 2 (batched): B1->B0 (pv0), B5->B2 (ch0)
    {
        GJobs3 j;
        j.j[0] = {B1, wt(1), pe_b2, B0, NP};
        j.j[1] = {B5, wt(3), ce_b2, B2, NC};
        j.j[2] = j.j[0];
        dim3 g = grd(NC); g.y = 2;
        hipLaunchKernelGGL(HIP_KERNEL_NAME(gemm_multi<4, true>), g, blk, 0, stream, j);
    }
    // RW_c / LW_v / RW_p (batched)
    {
        GJobs3 j;
        j.j[0] = {B2, wt(4), vc_bl, B1, NC};    // RW_c = ch0@wl+bl
        j.j[1] = {B0, wt(5), nullptr, B3, NP};  // LW_v = pv0@wr
        j.j[2] = {B0, wt(9), cv_bl, B6, NP};    // RW_p = pv0@cv_wl+bl
        dim3 g = grd(NC); g.y = 3;
        hipLaunchKernelGGL(HIP_KERNEL_NAME(gemm_multi<4, false>), g, blk, 0, stream, j);
    }

    // conv v->c
    hipLaunchKernelGGL(node_gather2, dim3(((size_t)NC * 32 + 255) / 256), blk, 0,
                       stream, off_c, cnt_c, AJ, B1, B3, B4, cntf, vc_sf, NC);
    gemm_rb<4, true, true, true><<<grd(NC), blk, 0, stream>>>(
        B4, B2, wt(6), wt(7), vc_bo1, cvec_vc, cntf, B5, NC);            // h_c
    gemm_rb<4, false, false, false><<<grd(NC), blk, 0, stream>>>(
        B5, nullptr, wt(8), nullptr, cx, nullptr, nullptr, B3, NC);      // LW_c

    // conv c->v
    hipLaunchKernelGGL(node_gather2, dim3(((size_t)NP * 32 + 255) / 256), blk, 0,
                       stream, off_p, cnt_p, AJ, B6, B3, B4, cntf, cv_sf, NP);
    gemm_rb<4, true, true, true><<<grd(NP), blk, 0, stream>>>(
        B4, B0, wt(11), wt(12), cv_bo1, cvec_cv, cntf, B1, NP);          // h_p

    // head on h_p with folded W1'=Wh, b1'=bh
    hipLaunchKernelGGL(head_fused, grd(NP), blk, 0, stream,
                       B1, wt(13), bh, out_w2, out_b2, (float*)d_out, NP);
}